// Round 12
// baseline (517.305 us; speedup 1.0000x reference)
//
#include <hip/hip_runtime.h>
#include <hip/hip_bf16.h>
#include <cstdint>
#include <cstddef>

#define N_NODES 100000
#define N_EDGES 1000000
#define F_IN 64
#define F_OUT 128
#define F_HID 512
#define NB 391          // buckets = ceil(100000 / 256)
#define BSH 8           // 256 nodes per bucket

typedef __attribute__((ext_vector_type(8))) short short8b;
typedef __attribute__((ext_vector_type(4))) short short4b;
typedef __attribute__((ext_vector_type(4))) float f32x4;

__device__ __forceinline__ float elu_f(float v) {
    return v > 0.0f ? v : __expf(v) - 1.0f;   // v_exp_f32 path, ~3 VALU ops
}

__device__ __forceinline__ unsigned short f2bf(float v) {
    __hip_bfloat16 b = __float2bfloat16(v);
    return *reinterpret_cast<unsigned short*>(&b);
}
__device__ __forceinline__ float bf2f(unsigned short u) {
    unsigned int w = (unsigned int)u << 16;
    return __uint_as_float(w);
}
// Truncation-based hi/lo split: 4 VALU ops, |err| <= 2^-16 |v|.
__device__ __forceinline__ void split_bf(float v, short& hi, short& lo) {
    unsigned short h = (unsigned short)(__float_as_uint(v) >> 16);
    float r = v - bf2f(h);
    hi = (short)h;
    lo = (short)(unsigned short)(__float_as_uint(r) >> 16);
}

// ---------------------------------------------------------------------------
// Degree histogram + exclusive scan.
// ---------------------------------------------------------------------------
__global__ __launch_bounds__(256) void hist_kernel(
    const int* __restrict__ src, const int* __restrict__ dst,
    int* __restrict__ deg_in, int* __restrict__ deg_out)
{
    int e = blockIdx.x * 256 + threadIdx.x;
    if (e < N_EDGES) {
        atomicAdd(&deg_in[dst[e]], 1);
        atomicAdd(&deg_out[src[e]], 1);
    }
}

__global__ __launch_bounds__(256) void scan_block_kernel(
    const int* __restrict__ deg, int* __restrict__ rowptr,
    int* __restrict__ blockSums, int n)
{
    __shared__ int sSum[256];
    int tid = threadIdx.x;
    int base = blockIdx.x * 1024 + tid * 4;
    int v0 = (base + 0 < n) ? deg[base + 0] : 0;
    int v1 = (base + 1 < n) ? deg[base + 1] : 0;
    int v2 = (base + 2 < n) ? deg[base + 2] : 0;
    int v3 = (base + 3 < n) ? deg[base + 3] : 0;
    int s = v0 + v1 + v2 + v3;
    sSum[tid] = s;
    __syncthreads();
    int incl = s;
    for (int off = 1; off < 256; off <<= 1) {
        int t = (tid >= off) ? sSum[tid - off] : 0;
        __syncthreads();
        incl += t;
        sSum[tid] = incl;
        __syncthreads();
    }
    int exclT = incl - s;
    if (base + 0 < n) rowptr[base + 0] = exclT;
    if (base + 1 < n) rowptr[base + 1] = exclT + v0;
    if (base + 2 < n) rowptr[base + 2] = exclT + v0 + v1;
    if (base + 3 < n) rowptr[base + 3] = exclT + v0 + v1 + v2;
    if (tid == 255) blockSums[blockIdx.x] = incl;
}

__global__ __launch_bounds__(128) void scan_top_kernel(int* blockSums, int nb)
{
    __shared__ int sh[128];
    int tid = threadIdx.x;
    int v = (tid < nb) ? blockSums[tid] : 0;
    sh[tid] = v;
    __syncthreads();
    int incl = v;
    for (int off = 1; off < 128; off <<= 1) {
        int t = (tid >= off) ? sh[tid - off] : 0;
        __syncthreads();
        incl += t;
        sh[tid] = incl;
        __syncthreads();
    }
    if (tid < nb) blockSums[tid] = incl - v;
}

// scan_add + bcur seeding fused (bcur[b] = final rowptr[b<<8]).
__global__ __launch_bounds__(256) void scan_add_kernel(
    int* __restrict__ rowptr, const int* __restrict__ blockSums, int n, int total,
    int* __restrict__ bcur)
{
    int i = blockIdx.x * 256 + threadIdx.x;
    if (i < n) {
        int v = rowptr[i] + blockSums[i >> 10];
        rowptr[i] = v;
        if ((i & 255) == 0) bcur[i >> BSH] = v;
    }
    if (i == 0) rowptr[n] = total;
}

// ---------------------------------------------------------------------------
// Multisplit CSR placement.
// ---------------------------------------------------------------------------
__global__ __launch_bounds__(512) void msplit_scatter_kernel(
    const int* __restrict__ keys, const int* __restrict__ vals,
    int* __restrict__ bcur, unsigned int* __restrict__ tmp)
{
    __shared__ int sCnt[NB];
    __shared__ int sBase[NB];
    int tid = threadIdx.x;
    int tile0 = blockIdx.x * 4096;

    for (int i = tid; i < NB; i += 512) sCnt[i] = 0;
    __syncthreads();

    int key[8], rank[8];
    #pragma unroll
    for (int j = 0; j < 8; ++j) {
        int e = tile0 + j * 512 + tid;
        key[j] = -1;
        if (e < N_EDGES) {
            int k = keys[e];
            key[j] = k;
            rank[j] = atomicAdd(&sCnt[k >> BSH], 1);
        }
    }
    __syncthreads();
    for (int i = tid; i < NB; i += 512) sBase[i] = atomicAdd(&bcur[i], sCnt[i]);
    __syncthreads();
    #pragma unroll
    for (int j = 0; j < 8; ++j) {
        int e = tile0 + j * 512 + tid;
        if (e < N_EDGES) {
            int k = key[j];
            unsigned int rec = ((unsigned int)vals[e] << BSH) | (unsigned int)(k & 255);
            tmp[sBase[k >> BSH] + rank[j]] = rec;
        }
    }
}

__global__ __launch_bounds__(256) void msplit_place_kernel(
    const unsigned int* __restrict__ tmp_in, const unsigned int* __restrict__ tmp_out,
    const int* __restrict__ rp_in, const int* __restrict__ rp_out,
    int* __restrict__ col_in, int* __restrict__ col_out,
    int* __restrict__ flag)
{
    __shared__ int sCur[256];
    int b = blockIdx.x;
    const unsigned int* tmp; const int* rp; int* col;
    if (b < NB) { tmp = tmp_in;  rp = rp_in;  col = col_in; }
    else        { b -= NB; tmp = tmp_out; rp = rp_out; col = col_out; }

    int k0 = b << BSH;
    int kend = (k0 + 256 < N_NODES) ? k0 + 256 : N_NODES;
    int nk = kend - k0;
    int tid = threadIdx.x;
    if (tid < nk) sCur[tid] = rp[k0 + tid];
    __syncthreads();

    int beg = rp[k0], end = rp[kend];
    for (int e = beg + tid; e < end; e += 256) {
        unsigned int rec = tmp[e];
        int k8 = (int)(rec & 255u);
        int v  = (int)(rec >> BSH);
        if (k8 < nk) {
            int pos = atomicAdd(&sCur[k8], 1);
            col[pos] = v;
        } else {
            atomicOr(flag, 1);
        }
    }
    __syncthreads();
    if (tid < nk && sCur[tid] != rp[k0 + tid + 1]) atomicOr(flag, 1);
}

__global__ __launch_bounds__(256) void place_repair_kernel(
    const int* __restrict__ flag,
    const int* __restrict__ src, const int* __restrict__ dst,
    const int* __restrict__ rp_in, const int* __restrict__ rp_out,
    int* __restrict__ cur_in, int* __restrict__ cur_out,
    int* __restrict__ col_in, int* __restrict__ col_out)
{
    if (flag[0] == 0) return;
    int e = blockIdx.x * 256 + threadIdx.x;
    if (e >= N_EDGES) return;
    int s = src[e], d = dst[e];
    int p = rp_in[d] + atomicAdd(&cur_in[d], 1);
    col_in[p] = s;
    int q = rp_out[s] + atomicAdd(&cur_out[s], 1);
    col_out[q] = d;
}

// ---------------------------------------------------------------------------
// x -> bf16 copy (halves gather L3 traffic). 4 elems/thread.
// ---------------------------------------------------------------------------
__global__ __launch_bounds__(256) void prep_x_kernel(
    const float* __restrict__ x, unsigned short* __restrict__ xbf)
{
    int i = blockIdx.x * 256 + threadIdx.x;
    int base = i * 4;
    if (base < N_NODES * F_IN) {
        float4 v = *reinterpret_cast<const float4*>(&x[base]);
        short4b o;
        o[0] = (short)f2bf(v.x);
        o[1] = (short)f2bf(v.y);
        o[2] = (short)f2bf(v.z);
        o[3] = (short)f2bf(v.w);
        *reinterpret_cast<short4b*>(&xbf[base]) = o;
    }
}

// ---------------------------------------------------------------------------
// Gather+mean from bf16 x: 2 B/lane row reads (128 B/row).
// ---------------------------------------------------------------------------
__global__ __launch_bounds__(256) void gather_mean_kernel(
    const unsigned short* __restrict__ xbf,
    const int* __restrict__ rowptr, const int* __restrict__ col,
    float* __restrict__ agg)
{
    int wid = blockIdx.x * 4 + (threadIdx.x >> 6);
    int f = threadIdx.x & 63;
    if (wid >= N_NODES) return;
    int beg = rowptr[wid];
    int end = rowptr[wid + 1];
    float acc = 0.0f;
    for (int e = beg; e < end; e += 8) {
        float a[8];
        #pragma unroll
        for (int i = 0; i < 8; ++i) {
            int idx = e + i;
            int c = col[idx < end ? idx : end - 1];
            a[i] = bf2f(xbf[(size_t)c * F_IN + f]);
            if (idx >= end) a[i] = 0.0f;
        }
        #pragma unroll
        for (int i = 0; i < 8; ++i) acc += a[i];
    }
    agg[(size_t)wid * F_IN + f] = acc / fmaxf((float)(end - beg), 1.0f);
}

// ---------------------------------------------------------------------------
// Weight fragment prep (unchanged).
// ---------------------------------------------------------------------------
__global__ __launch_bounds__(256) void prep_w_kernel(
    const float* __restrict__ W1, const float* __restrict__ W2,
    const float* __restrict__ Win, const float* __restrict__ Wout,
    unsigned short* __restrict__ W1Ahi, unsigned short* __restrict__ W1Alo,
    unsigned short* __restrict__ W2Ahi, unsigned short* __restrict__ W2Alo,
    unsigned short* __restrict__ WinAhi, unsigned short* __restrict__ WinAlo,
    unsigned short* __restrict__ WoutAhi, unsigned short* __restrict__ WoutAlo)
{
    int t = blockIdx.x * 256 + threadIdx.x;
    int lane = t & 63;
    int l15 = lane & 15, g = lane >> 4;
    if (t < 4096) {
        int ht = (t >> 6) & 31, ks = t >> 11;
        int m = ht * 16 + l15;
        int k0 = ks * 32 + g * 8;
        size_t o = ((size_t)(ht * 2 + ks) * 64 + lane) * 8;
        #pragma unroll
        for (int i = 0; i < 8; ++i) {
            float v = W1[(size_t)(k0 + i) * F_HID + m];
            unsigned short hi = f2bf(v);
            W1Ahi[o + i] = hi;
            W1Alo[o + i] = f2bf(v - bf2f(hi));
        }
    } else if (t < 12288) {
        int u = t - 4096;
        int ft = (u >> 6) & 7, ks2 = u >> 9;
        int m = ft * 16 + l15;
        int k0 = ks2 * 32 + g * 8;
        size_t o = ((size_t)(ks2 * 8 + ft) * 64 + lane) * 8;
        #pragma unroll
        for (int i = 0; i < 8; ++i) {
            float v = W2[(size_t)(k0 + i) * F_OUT + m];
            unsigned short hi = f2bf(v);
            W2Ahi[o + i] = hi;
            W2Alo[o + i] = f2bf(v - bf2f(hi));
        }
    } else if (t < 14336) {
        int u = t - 12288;
        const float* W = (u < 1024) ? Win : Wout;
        unsigned short* Ahi = (u < 1024) ? WinAhi : WoutAhi;
        unsigned short* Alo = (u < 1024) ? WinAlo : WoutAlo;
        u &= 1023;
        int ft = (u >> 6) & 7, ks = u >> 9;
        int m = ft * 16 + l15;
        int k0 = ks * 32 + g * 8;
        size_t o = ((size_t)(ks * 8 + ft) * 64 + lane) * 8;
        #pragma unroll
        for (int i = 0; i < 8; ++i) {
            float v = W[(size_t)(k0 + i) * F_OUT + m];
            unsigned short hi = f2bf(v);
            Ahi[o + i] = hi;
            Alo[o + i] = f2bf(v - bf2f(hi));
        }
    }
}

// ---------------------------------------------------------------------------
// SAGE linear via bf16x3 MFMA (unchanged, validated).
// ---------------------------------------------------------------------------
__global__ __launch_bounds__(256) void sage_lin_mfma_kernel(
    const float* __restrict__ agg,
    const unsigned short* __restrict__ WAhi, const unsigned short* __restrict__ WAlo,
    const float* __restrict__ b, float* __restrict__ out)
{
    int tid = threadIdx.x, lane = tid & 63, w = tid >> 6;
    int l15 = lane & 15, g = lane >> 4;
    int n = blockIdx.x * 64 + w * 16 + l15;
    int nc = (n > N_NODES - 1) ? N_NODES - 1 : n;

    short8b bhf[2], blf[2];
    #pragma unroll
    for (int ks = 0; ks < 2; ++ks) {
        const float* pa = &agg[(size_t)nc * F_IN + ks * 32 + g * 8];
        float4 v0 = *reinterpret_cast<const float4*>(pa);
        float4 v1 = *reinterpret_cast<const float4*>(pa + 4);
        float vv[8] = {v0.x, v0.y, v0.z, v0.w, v1.x, v1.y, v1.z, v1.w};
        short8b h8, l8;
        #pragma unroll
        for (int i = 0; i < 8; ++i) {
            short hh, ll;
            split_bf(vv[i], hh, ll);
            h8[i] = hh;
            l8[i] = ll;
        }
        bhf[ks] = h8;
        blf[ks] = l8;
    }

    #pragma unroll
    for (int ft = 0; ft < 8; ++ft) {
        f32x4 acc;
        {
            float4 bv = *reinterpret_cast<const float4*>(&b[ft * 16 + g * 4]);
            acc[0] = bv.x; acc[1] = bv.y; acc[2] = bv.z; acc[3] = bv.w;
        }
        #pragma unroll
        for (int ks = 0; ks < 2; ++ks) {
            size_t o = ((size_t)(ks * 8 + ft) * 64 + lane) * 8;
            short8b ah = *reinterpret_cast<const short8b*>(&WAhi[o]);
            short8b al = *reinterpret_cast<const short8b*>(&WAlo[o]);
            acc = __builtin_amdgcn_mfma_f32_16x16x32_bf16(ah, bhf[ks], acc, 0, 0, 0);
            acc = __builtin_amdgcn_mfma_f32_16x16x32_bf16(ah, blf[ks], acc, 0, 0, 0);
            acc = __builtin_amdgcn_mfma_f32_16x16x32_bf16(al, bhf[ks], acc, 0, 0, 0);
        }
        if (n < N_NODES) {
            float4 o4;
            o4.x = elu_f(acc[0]);
            o4.y = elu_f(acc[1]);
            o4.z = elu_f(acc[2]);
            o4.w = elu_f(acc[3]);
            *reinterpret_cast<float4*>(&out[(size_t)n * F_OUT + ft * 16 + g * 4]) = o4;
        }
    }
}

__global__ __launch_bounds__(256) void validate_sage_kernel(
    const float* __restrict__ agg,
    const float* __restrict__ W, const float* __restrict__ b,
    const float* __restrict__ outd, int* __restrict__ flag)
{
    int tid = threadIdx.x;
    #pragma unroll
    for (int ii = 0; ii < 2; ++ii) {
        int gid = tid * 2 + ii;
        int nn = gid >> 7, f = gid & 127;
        float acc = b[f];
        for (int k = 0; k < F_IN; ++k)
            acc = fmaf(agg[(size_t)nn * F_IN + k], W[(size_t)k * F_OUT + f], acc);
        float ref = elu_f(acc);
        float got = outd[(size_t)nn * F_OUT + f];
        if (!(fabsf(ref - got) <= 0.01f)) atomicOr(flag, 1);
    }
}

// ---------------------------------------------------------------------------
// Self MLP via bf16x3 MFMA v3: BARRIER-FREE.
// W fragments read directly from global (L2-resident, fragment-linear b128,
// same pattern as sage_lin_mfma). Only sH (h-tile exchange) stays in LDS and
// is strictly same-wave produce/consume -> zero __syncthreads.
// LDS 16 KB, VGPR ~80 -> ~6 blocks/CU resident.
// ---------------------------------------------------------------------------
__global__ __launch_bounds__(256, 4) void self_mlp_mfma_kernel(
    const float* __restrict__ x,
    const unsigned short* __restrict__ W1Ahi, const unsigned short* __restrict__ W1Alo,
    const unsigned short* __restrict__ W2Ahi, const unsigned short* __restrict__ W2Alo,
    const float* __restrict__ b1, const float* __restrict__ b2,
    float* __restrict__ out)
{
    __shared__ unsigned short sHhi[4096], sHlo[4096];

    int tid = threadIdx.x, lane = tid & 63, w = tid >> 6;
    int l15 = lane & 15, g = lane >> 4;
    int node0 = blockIdx.x * 128;

    short8b xhi[2][2], xlo[2][2];
    #pragma unroll
    for (int nt = 0; nt < 2; ++nt) {
        int n = node0 + (2 * w + nt) * 16 + l15;
        if (n > N_NODES - 1) n = N_NODES - 1;
        #pragma unroll
        for (int ks = 0; ks < 2; ++ks) {
            const float* px = &x[(size_t)n * F_IN + ks * 32 + g * 8];
            float4 v0 = *reinterpret_cast<const float4*>(px);
            float4 v1 = *reinterpret_cast<const float4*>(px + 4);
            float vv[8] = {v0.x, v0.y, v0.z, v0.w, v1.x, v1.y, v1.z, v1.w};
            short8b h8, l8;
            #pragma unroll
            for (int i = 0; i < 8; ++i) {
                short hh, ll;
                split_bf(vv[i], hh, ll);
                h8[i] = hh;
                l8[i] = ll;
            }
            xhi[nt][ks] = h8;
            xlo[nt][ks] = l8;
        }
    }

    f32x4 acc[8][2];
    #pragma unroll
    for (int ft = 0; ft < 8; ++ft) {
        float4 bv = *reinterpret_cast<const float4*>(&b2[ft * 16 + g * 4]);
        #pragma unroll
        for (int nt = 0; nt < 2; ++nt) {
            acc[ft][nt][0] = bv.x; acc[ft][nt][1] = bv.y;
            acc[ft][nt][2] = bv.z; acc[ft][nt][3] = bv.w;
        }
    }

    for (int c = 0; c < 16; ++c) {
        // Stage 1: h^T = W1^T @ x^T, W1 frags straight from global.
        #pragma unroll
        for (int ht = 0; ht < 2; ++ht) {
            #pragma unroll
            for (int nt = 0; nt < 2; ++nt) {
                f32x4 hacc;
                float4 b1v = *reinterpret_cast<const float4*>(&b1[c * 32 + ht * 16 + g * 4]);
                hacc[0] = b1v.x; hacc[1] = b1v.y; hacc[2] = b1v.z; hacc[3] = b1v.w;
                #pragma unroll
                for (int ks = 0; ks < 2; ++ks) {
                    size_t o = (size_t)c * 2048 + ((ht * 2 + ks) * 64 + lane) * 8;
                    short8b ah = *reinterpret_cast<const short8b*>(&W1Ahi[o]);
                    short8b al = *reinterpret_cast<const short8b*>(&W1Alo[o]);
                    hacc = __builtin_amdgcn_mfma_f32_16x16x32_bf16(ah, xhi[nt][ks], hacc, 0, 0, 0);
                    hacc = __builtin_amdgcn_mfma_f32_16x16x32_bf16(ah, xlo[nt][ks], hacc, 0, 0, 0);
                    hacc = __builtin_amdgcn_mfma_f32_16x16x32_bf16(al, xhi[nt][ks], hacc, 0, 0, 0);
                }
                int nodeL = (2 * w + nt) * 16 + l15;
                short4b ph, pl;
                #pragma unroll
                for (int r = 0; r < 4; ++r) {
                    float hv = elu_f(hacc[r]);
                    short hh, ll;
                    split_bf(hv, hh, ll);
                    ph[r] = hh;
                    pl[r] = ll;
                }
                int byte = nodeL * 64 + (ht * 16 + g * 4) * 2;
                byte ^= (nodeL & 7) << 4;
                *reinterpret_cast<short4b*>(reinterpret_cast<char*>(sHhi) + byte) = ph;
                *reinterpret_cast<short4b*>(reinterpret_cast<char*>(sHlo) + byte) = pl;
            }
        }

        // Stage 2: acc += W2^T @ h^T, W2 frags straight from global.
        short8b bh[2], bl[2];
        #pragma unroll
        for (int nt = 0; nt < 2; ++nt) {
            int nodeL = (2 * w + nt) * 16 + l15;
            int byte = (nodeL * 64 + g * 16) ^ ((nodeL & 7) << 4);
            bh[nt] = *reinterpret_cast<const short8b*>(reinterpret_cast<const char*>(sHhi) + byte);
            bl[nt] = *reinterpret_cast<const short8b*>(reinterpret_cast<const char*>(sHlo) + byte);
        }
        #pragma unroll
        for (int ft = 0; ft < 8; ++ft) {
            size_t o = ((size_t)(c * 8 + ft) * 64 + lane) * 8;
            short8b ah = *reinterpret_cast<const short8b*>(&W2Ahi[o]);
            short8b al = *reinterpret_cast<const short8b*>(&W2Alo[o]);
            #pragma unroll
            for (int nt = 0; nt < 2; ++nt) {
                acc[ft][nt] = __builtin_amdgcn_mfma_f32_16x16x32_bf16(ah, bh[nt], acc[ft][nt], 0, 0, 0);
                acc[ft][nt] = __builtin_amdgcn_mfma_f32_16x16x32_bf16(ah, bl[nt], acc[ft][nt], 0, 0, 0);
                acc[ft][nt] = __builtin_amdgcn_mfma_f32_16x16x32_bf16(al, bh[nt], acc[ft][nt], 0, 0, 0);
            }
        }
    }

    #pragma unroll
    for (int ft = 0; ft < 8; ++ft) {
        #pragma unroll
        for (int nt = 0; nt < 2; ++nt) {
            int n = node0 + (2 * w + nt) * 16 + l15;
            if (n < N_NODES) {
                float4 o;
                o.x = elu_f(acc[ft][nt][0]);
                o.y = elu_f(acc[ft][nt][1]);
                o.z = elu_f(acc[ft][nt][2]);
                o.w = elu_f(acc[ft][nt][3]);
                *reinterpret_cast<float4*>(&out[(size_t)n * F_OUT + ft * 16 + g * 4]) = o;
            }
        }
    }
}

__global__ __launch_bounds__(256) void validate_kernel(
    const float* __restrict__ x,
    const float* __restrict__ W1, const float* __restrict__ b1,
    const float* __restrict__ W2, const float* __restrict__ b2,
    const float* __restrict__ out_self, int* __restrict__ flag)
{
    __shared__ float h[4][512];
    int tid = threadIdx.x;
    #pragma unroll
    for (int ii = 0; ii < 8; ++ii) {
        int gid = tid * 8 + ii;
        int n = gid >> 9, j = gid & 511;
        float acc = b1[j];
        for (int k = 0; k < F_IN; ++k)
            acc = fmaf(x[(size_t)n * F_IN + k], W1[(size_t)k * F_HID + j], acc);
        h[n][j] = elu_f(acc);
    }
    __syncthreads();
    #pragma unroll
    for (int ii = 0; ii < 2; ++ii) {
        int gid = tid * 2 + ii;
        int n = gid >> 7, f = gid & 127;
        float acc = b2[f];
        for (int j = 0; j < F_HID; ++j)
            acc = fmaf(h[n][j], W2[(size_t)j * F_OUT + f], acc);
        float ref = elu_f(acc);
        float got = out_self[(size_t)n * F_OUT + f];
        if (!(fabsf(ref - got) <= 0.01f)) atomicOr(flag, 1);
    }
}

// ---------------------------------------------------------------------------
// Flag-gated repairs.
// ---------------------------------------------------------------------------
__global__ __launch_bounds__(256) void gather_repair_kernel(
    const int* __restrict__ flag,
    const float* __restrict__ x,
    const int* __restrict__ rowptr, const int* __restrict__ col,
    float* __restrict__ agg)
{
    if (flag[0] == 0) return;
    int f = threadIdx.x & 63;
    for (int bb = blockIdx.x; bb < 25000; bb += gridDim.x) {
        int wid = bb * 4 + (threadIdx.x >> 6);
        if (wid >= N_NODES) continue;
        int beg = rowptr[wid];
        int end = rowptr[wid + 1];
        float acc = 0.0f;
        for (int e = beg; e < end; ++e)
            acc += x[(size_t)col[e] * F_IN + f];
        agg[(size_t)wid * F_IN + f] = acc / fmaxf((float)(end - beg), 1.0f);
    }
}

__global__ __launch_bounds__(256) void sage_lin_repair_kernel(
    const int* __restrict__ flag,
    const float* __restrict__ agg,
    const float* __restrict__ W, const float* __restrict__ b,
    float* __restrict__ out)
{
    if (flag[0] == 0) return;

    __shared__ float sW[F_IN][F_OUT];
    __shared__ float sA[16][68];

    int tid = threadIdx.x;
    int og = tid & 15;
    int nl = tid >> 4;

    for (int bb = blockIdx.x; bb < 6250; bb += gridDim.x) {
        int node0 = bb * 16;
        __syncthreads();
        #pragma unroll
        for (int it = 0; it < 8; ++it) {
            int i = tid + it * 256;
            int k = (i * 4) >> 7, ff = (i * 4) & 127;
            *reinterpret_cast<float4*>(&sW[k][ff]) =
                *reinterpret_cast<const float4*>(&W[(size_t)i * 4]);
        }
        {
            int nn = node0 + (tid >> 4), c4 = tid & 15;
            *reinterpret_cast<float4*>(&sA[tid >> 4][c4 * 4]) =
                *reinterpret_cast<const float4*>(&agg[(size_t)nn * F_IN + c4 * 4]);
        }
        __syncthreads();

        int n = node0 + nl;
        float acc[8];
        {
            float4 bl = *reinterpret_cast<const float4*>(&b[og * 4]);
            float4 bh = *reinterpret_cast<const float4*>(&b[64 + og * 4]);
            acc[0] = bl.x; acc[1] = bl.y; acc[2] = bl.z; acc[3] = bl.w;
            acc[4] = bh.x; acc[5] = bh.y; acc[6] = bh.z; acc[7] = bh.w;
        }
        for (int k = 0; k < F_IN; ++k) {
            float a = sA[nl][k];
            float4 w0 = *reinterpret_cast<const float4*>(&sW[k][og * 4]);
            float4 w1 = *reinterpret_cast<const float4*>(&sW[k][64 + og * 4]);
            acc[0] = fmaf(a, w0.x, acc[0]);
            acc[1] = fmaf(a, w0.y, acc[1]);
            acc[2] = fmaf(a, w0.z, acc[2]);
            acc[3] = fmaf(a, w0.w, acc[3]);
            acc[4] = fmaf(a, w1.x, acc[4]);
            acc[5] = fmaf(a, w1.y, acc[5]);
            acc[6] = fmaf(a, w1.z, acc[6]);
            acc[7] = fmaf(a, w1.w, acc[7]);
        }
        float4 o0 = make_float4(elu_f(acc[0]), elu_f(acc[1]), elu_f(acc[2]), elu_f(acc[3]));
        float4 o1 = make_float4(elu_f(acc[4]), elu_f(acc[5]), elu_f(acc[6]), elu_f(acc[7]));
        *reinterpret_cast<float4*>(&out[(size_t)n * F_OUT + og * 4]) = o0;
        *reinterpret_cast<float4*>(&out[(size_t)n * F_OUT + 64 + og * 4]) = o1;
    }
}

__global__ __launch_bounds__(256, 3) void self_mlp_repair_kernel(
    const int* __restrict__ flag,
    const float* __restrict__ x,
    const float* __restrict__ W1, const float* __restrict__ b1,
    const float* __restrict__ W2, const float* __restrict__ b2,
    float* __restrict__ out)
{
    if (flag[0] == 0) return;

    __shared__ float sXT[F_IN][128];
    __shared__ float sW1[F_IN][16];
    __shared__ float sHT[16][128];
    __shared__ float sW2[16][128];
    __shared__ float sb1[16];

    int tid = threadIdx.x;
    int node0 = blockIdx.x * 128;

    #pragma unroll
    for (int it = 0; it < 8; ++it) {
        int fid = tid + it * 256;
        int node = fid & 127, k4 = fid >> 7;
        int n = node0 + node;
        if (n > N_NODES - 1) n = N_NODES - 1;
        float4 v = *reinterpret_cast<const float4*>(&x[(size_t)n * F_IN + k4 * 4]);
        sXT[k4 * 4 + 0][node] = v.x;
        sXT[k4 * 4 + 1][node] = v.y;
        sXT[k4 * 4 + 2][node] = v.z;
        sXT[k4 * 4 + 3][node] = v.w;
    }

    int og = tid & 15;
    int ng = tid >> 4;
    int ng1 = tid & 31;
    int hg = tid >> 5;

    float acc[8][8];
    {
        float4 bl = *reinterpret_cast<const float4*>(&b2[og * 4]);
        float4 bh = *reinterpret_cast<const float4*>(&b2[64 + og * 4]);
        #pragma unroll
        for (int i = 0; i < 8; ++i) {
            acc[i][0] = bl.x; acc[i][1] = bl.y; acc[i][2] = bl.z; acc[i][3] = bl.w;
            acc[i][4] = bh.x; acc[i][5] = bh.y; acc[i][6] = bh.z; acc[i][7] = bh.w;
        }
    }

    for (int c = 0; c < 32; ++c) {
        int hid0 = c * 16;
        __syncthreads();

        {
            int k = tid >> 2, h4 = tid & 3;
            float4 v = *reinterpret_cast<const float4*>(&W1[(size_t)k * F_HID + hid0 + h4 * 4]);
            *reinterpret_cast<float4*>(&sW1[k][h4 * 4]) = v;
        }
        #pragma unroll
        for (int it = 0; it < 2; ++it) {
            int fid = tid + it * 256;
            int j = fid >> 5, f4 = fid & 31;
            float4 v = *reinterpret_cast<const float4*>(&W2[(size_t)(hid0 + j) * F_OUT + f4 * 4]);
            *reinterpret_cast<float4*>(&sW2[j][f4 * 4]) = v;
        }
        if (tid < 16) sb1[tid] = b1[hid0 + tid];
        __syncthreads();

        {
            float h0[4], h1[4];
            float bb0 = sb1[hg * 2], bb1 = sb1[hg * 2 + 1];
            #pragma unroll
            for (int i = 0; i < 4; ++i) { h0[i] = bb0; h1[i] = bb1; }
            #pragma unroll 8
            for (int k = 0; k < F_IN; ++k) {
                float4 a = *reinterpret_cast<const float4*>(&sXT[k][ng1 * 4]);
                float w0 = sW1[k][hg * 2];
                float w1 = sW1[k][hg * 2 + 1];
                h0[0] = fmaf(w0, a.x, h0[0]);
                h0[1] = fmaf(w0, a.y, h0[1]);
                h0[2] = fmaf(w0, a.z, h0[2]);
                h0[3] = fmaf(w0, a.w, h0[3]);
                h1[0] = fmaf(w1, a.x, h1[0]);
                h1[1] = fmaf(w1, a.y, h1[1]);
                h1[2] = fmaf(w1, a.z, h1[2]);
                h1[3] = fmaf(w1, a.w, h1[3]);
            }
            float4 o0 = make_float4(elu_f(h0[0]), elu_f(h0[1]), elu_f(h0[2]), elu_f(h0[3]));
            float4 o1 = make_float4(elu_f(h1[0]), elu_f(h1[1]), elu_f(h1[2]), elu_f(h1[3]));
            *reinterpret_cast<float4*>(&sHT[hg * 2][ng1 * 4]) = o0;
            *reinterpret_cast<float4*>(&sHT[hg * 2 + 1][ng1 * 4]) = o1;
        }
        __syncthreads();

        #pragma unroll 2
        for (int k = 0; k < 16; ++k) {
            float4 ha = *reinterpret_cast<const float4*>(&sHT[k][ng * 4]);
            float4 hb = *reinterpret_cast<const float4*>(&sHT[k][64 + ng * 4]);
            float4 wa = *reinterpret_cast<const float4*>(&sW2[k][og * 4]);
            float4 wb = *reinterpret_cast<const float4*>(&sW2[k][64 + og * 4]);
            float hv[8] = {ha.x, ha.y, ha.z, ha.w, hb.x, hb.y, hb.z, hb.w};
            float wv[8] = {wa.x, wa.y, wa.z, wa.w, wb.x, wb.y, wb.z, wb.w};
            #pragma unroll
            for (int i = 0; i < 8; ++i) {
                #pragma unroll
                for (int j = 0; j < 8; ++j) {
                    acc[i][j] = fmaf(hv[i], wv[j], acc[i][j]);
                }
            }
        }
    }

    #pragma unroll
    for (int i = 0; i < 8; ++i) {
        int n = node0 + (i < 4 ? ng * 4 + i : 64 + ng * 4 + (i - 4));
        if (n < N_NODES) {
            float4 o0 = make_float4(elu_f(acc[i][0]), elu_f(acc[i][1]),
                                    elu_f(acc[i][2]), elu_f(acc[i][3]));
            float4 o1 = make_float4(elu_f(acc[i][4]), elu_f(acc[i][5]),
                                    elu_f(acc[i][6]), elu_f(acc[i][7]));
            *reinterpret_cast<float4*>(&out[(size_t)n * F_OUT + og * 4]) = o0;
            *reinterpret_cast<float4*>(&out[(size_t)n * F_OUT + 64 + og * 4]) = o1;
        }
    }
}

// ---------------------------------------------------------------------------

extern "C" void kernel_launch(void* const* d_in, const int* in_sizes, int n_in,
                              void* d_out, int out_size, void* d_ws, size_t ws_size,
                              hipStream_t stream) {
    const float* x     = (const float*)d_in[0];
    const int*   ei    = (const int*)d_in[1];
    const float* W_in  = (const float*)d_in[2];
    const float* b_in  = (const float*)d_in[3];
    const float* W_out = (const float*)d_in[4];
    const float* b_out = (const float*)d_in[5];
    const float* W1    = (const float*)d_in[6];
    const float* b1    = (const float*)d_in[7];
    const float* W2    = (const float*)d_in[8];
    const float* b2    = (const float*)d_in[9];
    float* out = (float*)d_out;

    const int* src = ei;
    const int* dst = ei + N_EDGES;

    int* I = (int*)d_ws;
    int* rowptr_in  = I;                       // 100001
    int* rowptr_out = I + 100001;              // 100001
    int* col_in     = I + 200002;              // 1,000,000
    int* col_out    = I + 1200002;             // 1,000,000
    int* deg_in     = I + 2200002;             // 100,000  <- zeroed start
    int* deg_out    = I + 2300002;             // 100,000
    int* cur_in     = I + 2400002;             // 100,000  (repair scratch)
    int* cur_out    = I + 2500002;             // 100,000  <- zeroed end
    int* bsum_in    = I + 2600002;             // 128
    int* bsum_out   = I + 2600130;             // 128
    int* flagM      = I + 2600260;             // self MFMA
    int* flagS      = I + 2600261;             // sage MFMA
    int* flagC      = I + 2600262;             // CSR multisplit
    float* agg      = (float*)(I + 2600512);   // 100000*64 floats (25.6 MB)
    unsigned short* WF = (unsigned short*)(I + 9000512);
    unsigned short* W1Ahi  = WF;
    unsigned short* W1Alo  = WF + 32768;
    unsigned short* W2Ahi  = WF + 65536;
    unsigned short* W2Alo  = WF + 131072;
    unsigned short* WinAhi = WF + 196608;
    unsigned short* WinAlo = WF + 204800;
    unsigned short* WoutAhi= WF + 212992;
    unsigned short* WoutAlo= WF + 221184;      // ends at 229376 halfs
    unsigned short* xbf    = (unsigned short*)(I + 9120512);  // 6.4M halfs (12.8 MB)

    unsigned int* tmp_in  = (unsigned int*)agg;            // alias agg (dead until gather)
    unsigned int* tmp_out = (unsigned int*)agg + 1000000;
    int* bcur_in  = deg_in;                                // alias deg (dead after scans)
    int* bcur_out = deg_out;

    hipMemsetAsync(deg_in, 0, 400000 * sizeof(int), stream);
    hipMemsetAsync(flagM, 0, 3 * sizeof(int), stream);

    prep_w_kernel<<<56, 256, 0, stream>>>(W1, W2, W_in, W_out,
                                          W1Ahi, W1Alo, W2Ahi, W2Alo,
                                          WinAhi, WinAlo, WoutAhi, WoutAlo);
    prep_x_kernel<<<6250, 256, 0, stream>>>(x, xbf);

    const int eb = (N_EDGES + 255) / 256;      // 3907
    hist_kernel<<<eb, 256, 0, stream>>>(src, dst, deg_in, deg_out);

    const int sb = (N_NODES + 1023) / 1024;    // 98
    scan_block_kernel<<<sb, 256, 0, stream>>>(deg_in, rowptr_in, bsum_in, N_NODES);
    scan_block_kernel<<<sb, 256, 0, stream>>>(deg_out, rowptr_out, bsum_out, N_NODES);
    scan_top_kernel<<<1, 128, 0, stream>>>(bsum_in, sb);
    scan_top_kernel<<<1, 128, 0, stream>>>(bsum_out, sb);
    const int ab = (N_NODES + 255) / 256;      // 391
    scan_add_kernel<<<ab, 256, 0, stream>>>(rowptr_in, bsum_in, N_NODES, N_EDGES, bcur_in);
    scan_add_kernel<<<ab, 256, 0, stream>>>(rowptr_out, bsum_out, N_NODES, N_EDGES, bcur_out);

    const int p1b = (N_EDGES + 4095) / 4096;   // 245
    msplit_scatter_kernel<<<p1b, 512, 0, stream>>>(dst, src, bcur_in, tmp_in);
    msplit_scatter_kernel<<<p1b, 512, 0, stream>>>(src, dst, bcur_out, tmp_out);
    msplit_place_kernel<<<2 * NB, 256, 0, stream>>>(tmp_in, tmp_out,
                                                    rowptr_in, rowptr_out,
                                                    col_in, col_out, flagC);
    place_repair_kernel<<<eb, 256, 0, stream>>>(flagC, src, dst,
                                                rowptr_in, rowptr_out,
                                                cur_in, cur_out, col_in, col_out);

    const int gb = (N_NODES + 3) / 4;          // 25000
    const int mb = (N_NODES + 63) / 64;        // 1563
    float* out_in   = out;
    float* out_out  = out + (size_t)N_NODES * F_OUT;
    float* out_self = out + 2 * (size_t)N_NODES * F_OUT;

    gather_mean_kernel<<<gb, 256, 0, stream>>>(xbf, rowptr_in, col_in, agg);
    sage_lin_mfma_kernel<<<mb, 256, 0, stream>>>(agg, WinAhi, WinAlo, b_in, out_in);
    validate_sage_kernel<<<1, 256, 0, stream>>>(agg, W_in, b_in, out_in, flagS);

    gather_mean_kernel<<<gb, 256, 0, stream>>>(xbf, rowptr_out, col_out, agg);
    sage_lin_mfma_kernel<<<mb, 256, 0, stream>>>(agg, WoutAhi, WoutAlo, b_out, out_out);
    validate_sage_kernel<<<1, 256, 0, stream>>>(agg, W_out, b_out, out_out, flagS);

    self_mlp_mfma_kernel<<<782, 256, 0, stream>>>(x, W1Ahi, W1Alo, W2Ahi, W2Alo,
                                                  b1, b2, out_self);
    validate_kernel<<<1, 256, 0, stream>>>(x, W1, b1, W2, b2, out_self, flagM);

    self_mlp_repair_kernel<<<782, 256, 0, stream>>>(flagM, x, W1, b1, W2, b2, out_self);
    gather_repair_kernel<<<2048, 256, 0, stream>>>(flagS, x, rowptr_in, col_in, agg);
    sage_lin_repair_kernel<<<2048, 256, 0, stream>>>(flagS, agg, W_in, b_in, out_in);
    gather_repair_kernel<<<2048, 256, 0, stream>>>(flagS, x, rowptr_out, col_out, agg);
    sage_lin_repair_kernel<<<2048, 256, 0, stream>>>(flagS, agg, W_out, b_out, out_out);
}

// Round 14
// 468.690 us; speedup vs baseline: 1.1037x; 1.1037x over previous
//
#include <hip/hip_runtime.h>
#include <hip/hip_bf16.h>
#include <cstdint>
#include <cstddef>

#define N_NODES 100000
#define N_EDGES 1000000
#define F_IN 64
#define F_OUT 128
#define F_HID 512
#define NB 391          // buckets = ceil(100000 / 256)
#define BSH 8           // 256 nodes per bucket

typedef __attribute__((ext_vector_type(8))) short short8b;
typedef __attribute__((ext_vector_type(4))) short short4b;
typedef __attribute__((ext_vector_type(4))) float f32x4;

__device__ __forceinline__ float elu_f(float v) {
    return v > 0.0f ? v : __expf(v) - 1.0f;
}

__device__ __forceinline__ unsigned short f2bf(float v) {
    __hip_bfloat16 b = __float2bfloat16(v);
    return *reinterpret_cast<unsigned short*>(&b);
}
__device__ __forceinline__ float bf2f(unsigned short u) {
    unsigned int w = (unsigned int)u << 16;
    return __uint_as_float(w);
}
// Truncation-based hi/lo split: 4 VALU ops, |err| <= 2^-16 |v|.
__device__ __forceinline__ void split_bf(float v, short& hi, short& lo) {
    unsigned short h = (unsigned short)(__float_as_uint(v) >> 16);
    float r = v - bf2f(h);
    hi = (short)h;
    lo = (short)(unsigned short)(__float_as_uint(r) >> 16);
}

// ---------------------------------------------------------------------------
// Degree histogram + exclusive scan.
// ---------------------------------------------------------------------------
__global__ __launch_bounds__(256) void hist_kernel(
    const int* __restrict__ src, const int* __restrict__ dst,
    int* __restrict__ deg_in, int* __restrict__ deg_out)
{
    int e = blockIdx.x * 256 + threadIdx.x;
    if (e < N_EDGES) {
        atomicAdd(&deg_in[dst[e]], 1);
        atomicAdd(&deg_out[src[e]], 1);
    }
}

__global__ __launch_bounds__(256) void scan_block_kernel(
    const int* __restrict__ deg, int* __restrict__ rowptr,
    int* __restrict__ blockSums, int n)
{
    __shared__ int sSum[256];
    int tid = threadIdx.x;
    int base = blockIdx.x * 1024 + tid * 4;
    int v0 = (base + 0 < n) ? deg[base + 0] : 0;
    int v1 = (base + 1 < n) ? deg[base + 1] : 0;
    int v2 = (base + 2 < n) ? deg[base + 2] : 0;
    int v3 = (base + 3 < n) ? deg[base + 3] : 0;
    int s = v0 + v1 + v2 + v3;
    sSum[tid] = s;
    __syncthreads();
    int incl = s;
    for (int off = 1; off < 256; off <<= 1) {
        int t = (tid >= off) ? sSum[tid - off] : 0;
        __syncthreads();
        incl += t;
        sSum[tid] = incl;
        __syncthreads();
    }
    int exclT = incl - s;
    if (base + 0 < n) rowptr[base + 0] = exclT;
    if (base + 1 < n) rowptr[base + 1] = exclT + v0;
    if (base + 2 < n) rowptr[base + 2] = exclT + v0 + v1;
    if (base + 3 < n) rowptr[base + 3] = exclT + v0 + v1 + v2;
    if (tid == 255) blockSums[blockIdx.x] = incl;
}

__global__ __launch_bounds__(128) void scan_top_kernel(int* blockSums, int nb)
{
    __shared__ int sh[128];
    int tid = threadIdx.x;
    int v = (tid < nb) ? blockSums[tid] : 0;
    sh[tid] = v;
    __syncthreads();
    int incl = v;
    for (int off = 1; off < 128; off <<= 1) {
        int t = (tid >= off) ? sh[tid - off] : 0;
        __syncthreads();
        incl += t;
        sh[tid] = incl;
        __syncthreads();
    }
    if (tid < nb) blockSums[tid] = incl - v;
}

// scan_add + bcur seeding fused (bcur[b] = final rowptr[b<<8]).
__global__ __launch_bounds__(256) void scan_add_kernel(
    int* __restrict__ rowptr, const int* __restrict__ blockSums, int n, int total,
    int* __restrict__ bcur)
{
    int i = blockIdx.x * 256 + threadIdx.x;
    if (i < n) {
        int v = rowptr[i] + blockSums[i >> 10];
        rowptr[i] = v;
        if ((i & 255) == 0) bcur[i >> BSH] = v;
    }
    if (i == 0) rowptr[n] = total;
}

// ---------------------------------------------------------------------------
// Multisplit CSR placement.
// ---------------------------------------------------------------------------
__global__ __launch_bounds__(512) void msplit_scatter_kernel(
    const int* __restrict__ keys, const int* __restrict__ vals,
    int* __restrict__ bcur, unsigned int* __restrict__ tmp)
{
    __shared__ int sCnt[NB];
    __shared__ int sBase[NB];
    int tid = threadIdx.x;
    int tile0 = blockIdx.x * 4096;

    for (int i = tid; i < NB; i += 512) sCnt[i] = 0;
    __syncthreads();

    int key[8], rank[8];
    #pragma unroll
    for (int j = 0; j < 8; ++j) {
        int e = tile0 + j * 512 + tid;
        key[j] = -1;
        if (e < N_EDGES) {
            int k = keys[e];
            key[j] = k;
            rank[j] = atomicAdd(&sCnt[k >> BSH], 1);
        }
    }
    __syncthreads();
    for (int i = tid; i < NB; i += 512) sBase[i] = atomicAdd(&bcur[i], sCnt[i]);
    __syncthreads();
    #pragma unroll
    for (int j = 0; j < 8; ++j) {
        int e = tile0 + j * 512 + tid;
        if (e < N_EDGES) {
            int k = key[j];
            unsigned int rec = ((unsigned int)vals[e] << BSH) | (unsigned int)(k & 255);
            tmp[sBase[k >> BSH] + rank[j]] = rec;
        }
    }
}

__global__ __launch_bounds__(256) void msplit_place_kernel(
    const unsigned int* __restrict__ tmp_in, const unsigned int* __restrict__ tmp_out,
    const int* __restrict__ rp_in, const int* __restrict__ rp_out,
    int* __restrict__ col_in, int* __restrict__ col_out,
    int* __restrict__ flag)
{
    __shared__ int sCur[256];
    int b = blockIdx.x;
    const unsigned int* tmp; const int* rp; int* col;
    if (b < NB) { tmp = tmp_in;  rp = rp_in;  col = col_in; }
    else        { b -= NB; tmp = tmp_out; rp = rp_out; col = col_out; }

    int k0 = b << BSH;
    int kend = (k0 + 256 < N_NODES) ? k0 + 256 : N_NODES;
    int nk = kend - k0;
    int tid = threadIdx.x;
    if (tid < nk) sCur[tid] = rp[k0 + tid];
    __syncthreads();

    int beg = rp[k0], end = rp[kend];
    for (int e = beg + tid; e < end; e += 256) {
        unsigned int rec = tmp[e];
        int k8 = (int)(rec & 255u);
        int v  = (int)(rec >> BSH);
        if (k8 < nk) {
            int pos = atomicAdd(&sCur[k8], 1);
            col[pos] = v;
        } else {
            atomicOr(flag, 1);
        }
    }
    __syncthreads();
    if (tid < nk && sCur[tid] != rp[k0 + tid + 1]) atomicOr(flag, 1);
}

__global__ __launch_bounds__(256) void place_repair_kernel(
    const int* __restrict__ flag,
    const int* __restrict__ src, const int* __restrict__ dst,
    const int* __restrict__ rp_in, const int* __restrict__ rp_out,
    int* __restrict__ cur_in, int* __restrict__ cur_out,
    int* __restrict__ col_in, int* __restrict__ col_out)
{
    if (flag[0] == 0) return;
    int e = blockIdx.x * 256 + threadIdx.x;
    if (e >= N_EDGES) return;
    int s = src[e], d = dst[e];
    int p = rp_in[d] + atomicAdd(&cur_in[d], 1);
    col_in[p] = s;
    int q = rp_out[s] + atomicAdd(&cur_out[s], 1);
    col_out[q] = d;
}

// ---------------------------------------------------------------------------
// x -> bf16 copy (halves gather L3 traffic). 4 elems/thread.
// ---------------------------------------------------------------------------
__global__ __launch_bounds__(256) void prep_x_kernel(
    const float* __restrict__ x, unsigned short* __restrict__ xbf)
{
    int i = blockIdx.x * 256 + threadIdx.x;
    int base = i * 4;
    if (base < N_NODES * F_IN) {
        float4 v = *reinterpret_cast<const float4*>(&x[base]);
        short4b o;
        o[0] = (short)f2bf(v.x);
        o[1] = (short)f2bf(v.y);
        o[2] = (short)f2bf(v.z);
        o[3] = (short)f2bf(v.w);
        *reinterpret_cast<short4b*>(&xbf[base]) = o;
    }
}

// ---------------------------------------------------------------------------
// Gather+mean from bf16 x: 2 B/lane row reads (128 B/row).
// ---------------------------------------------------------------------------
__global__ __launch_bounds__(256) void gather_mean_kernel(
    const unsigned short* __restrict__ xbf,
    const int* __restrict__ rowptr, const int* __restrict__ col,
    float* __restrict__ agg)
{
    int wid = blockIdx.x * 4 + (threadIdx.x >> 6);
    int f = threadIdx.x & 63;
    if (wid >= N_NODES) return;
    int beg = rowptr[wid];
    int end = rowptr[wid + 1];
    float acc = 0.0f;
    for (int e = beg; e < end; e += 8) {
        float a[8];
        #pragma unroll
        for (int i = 0; i < 8; ++i) {
            int idx = e + i;
            int c = col[idx < end ? idx : end - 1];
            a[i] = bf2f(xbf[(size_t)c * F_IN + f]);
            if (idx >= end) a[i] = 0.0f;
        }
        #pragma unroll
        for (int i = 0; i < 8; ++i) acc += a[i];
    }
    agg[(size_t)wid * F_IN + f] = acc / fmaxf((float)(end - beg), 1.0f);
}

// ---------------------------------------------------------------------------
// Weight fragment prep (unchanged).
// ---------------------------------------------------------------------------
__global__ __launch_bounds__(256) void prep_w_kernel(
    const float* __restrict__ W1, const float* __restrict__ W2,
    const float* __restrict__ Win, const float* __restrict__ Wout,
    unsigned short* __restrict__ W1Ahi, unsigned short* __restrict__ W1Alo,
    unsigned short* __restrict__ W2Ahi, unsigned short* __restrict__ W2Alo,
    unsigned short* __restrict__ WinAhi, unsigned short* __restrict__ WinAlo,
    unsigned short* __restrict__ WoutAhi, unsigned short* __restrict__ WoutAlo)
{
    int t = blockIdx.x * 256 + threadIdx.x;
    int lane = t & 63;
    int l15 = lane & 15, g = lane >> 4;
    if (t < 4096) {
        int ht = (t >> 6) & 31, ks = t >> 11;
        int m = ht * 16 + l15;
        int k0 = ks * 32 + g * 8;
        size_t o = ((size_t)(ht * 2 + ks) * 64 + lane) * 8;
        #pragma unroll
        for (int i = 0; i < 8; ++i) {
            float v = W1[(size_t)(k0 + i) * F_HID + m];
            unsigned short hi = f2bf(v);
            W1Ahi[o + i] = hi;
            W1Alo[o + i] = f2bf(v - bf2f(hi));
        }
    } else if (t < 12288) {
        int u = t - 4096;
        int ft = (u >> 6) & 7, ks2 = u >> 9;
        int m = ft * 16 + l15;
        int k0 = ks2 * 32 + g * 8;
        size_t o = ((size_t)(ks2 * 8 + ft) * 64 + lane) * 8;
        #pragma unroll
        for (int i = 0; i < 8; ++i) {
            float v = W2[(size_t)(k0 + i) * F_OUT + m];
            unsigned short hi = f2bf(v);
            W2Ahi[o + i] = hi;
            W2Alo[o + i] = f2bf(v - bf2f(hi));
        }
    } else if (t < 14336) {
        int u = t - 12288;
        const float* W = (u < 1024) ? Win : Wout;
        unsigned short* Ahi = (u < 1024) ? WinAhi : WoutAhi;
        unsigned short* Alo = (u < 1024) ? WinAlo : WoutAlo;
        u &= 1023;
        int ft = (u >> 6) & 7, ks = u >> 9;
        int m = ft * 16 + l15;
        int k0 = ks * 32 + g * 8;
        size_t o = ((size_t)(ks * 8 + ft) * 64 + lane) * 8;
        #pragma unroll
        for (int i = 0; i < 8; ++i) {
            float v = W[(size_t)(k0 + i) * F_OUT + m];
            unsigned short hi = f2bf(v);
            Ahi[o + i] = hi;
            Alo[o + i] = f2bf(v - bf2f(hi));
        }
    }
}

// ---------------------------------------------------------------------------
// SAGE linear via bf16x3 MFMA (unchanged, validated).
// ---------------------------------------------------------------------------
__global__ __launch_bounds__(256) void sage_lin_mfma_kernel(
    const float* __restrict__ agg,
    const unsigned short* __restrict__ WAhi, const unsigned short* __restrict__ WAlo,
    const float* __restrict__ b, float* __restrict__ out)
{
    int tid = threadIdx.x, lane = tid & 63, w = tid >> 6;
    int l15 = lane & 15, g = lane >> 4;
    int n = blockIdx.x * 64 + w * 16 + l15;
    int nc = (n > N_NODES - 1) ? N_NODES - 1 : n;

    short8b bhf[2], blf[2];
    #pragma unroll
    for (int ks = 0; ks < 2; ++ks) {
        const float* pa = &agg[(size_t)nc * F_IN + ks * 32 + g * 8];
        float4 v0 = *reinterpret_cast<const float4*>(pa);
        float4 v1 = *reinterpret_cast<const float4*>(pa + 4);
        float vv[8] = {v0.x, v0.y, v0.z, v0.w, v1.x, v1.y, v1.z, v1.w};
        short8b h8, l8;
        #pragma unroll
        for (int i = 0; i < 8; ++i) {
            short hh, ll;
            split_bf(vv[i], hh, ll);
            h8[i] = hh;
            l8[i] = ll;
        }
        bhf[ks] = h8;
        blf[ks] = l8;
    }

    #pragma unroll
    for (int ft = 0; ft < 8; ++ft) {
        f32x4 acc;
        {
            float4 bv = *reinterpret_cast<const float4*>(&b[ft * 16 + g * 4]);
            acc[0] = bv.x; acc[1] = bv.y; acc[2] = bv.z; acc[3] = bv.w;
        }
        #pragma unroll
        for (int ks = 0; ks < 2; ++ks) {
            size_t o = ((size_t)(ks * 8 + ft) * 64 + lane) * 8;
            short8b ah = *reinterpret_cast<const short8b*>(&WAhi[o]);
            short8b al = *reinterpret_cast<const short8b*>(&WAlo[o]);
            acc = __builtin_amdgcn_mfma_f32_16x16x32_bf16(ah, bhf[ks], acc, 0, 0, 0);
            acc = __builtin_amdgcn_mfma_f32_16x16x32_bf16(ah, blf[ks], acc, 0, 0, 0);
            acc = __builtin_amdgcn_mfma_f32_16x16x32_bf16(al, bhf[ks], acc, 0, 0, 0);
        }
        if (n < N_NODES) {
            float4 o4;
            o4.x = elu_f(acc[0]);
            o4.y = elu_f(acc[1]);
            o4.z = elu_f(acc[2]);
            o4.w = elu_f(acc[3]);
            *reinterpret_cast<float4*>(&out[(size_t)n * F_OUT + ft * 16 + g * 4]) = o4;
        }
    }
}

__global__ __launch_bounds__(256) void validate_sage_kernel(
    const float* __restrict__ agg,
    const float* __restrict__ W, const float* __restrict__ b,
    const float* __restrict__ outd, int* __restrict__ flag)
{
    int tid = threadIdx.x;
    #pragma unroll
    for (int ii = 0; ii < 2; ++ii) {
        int gid = tid * 2 + ii;
        int nn = gid >> 7, f = gid & 127;
        float acc = b[f];
        for (int k = 0; k < F_IN; ++k)
            acc = fmaf(agg[(size_t)nn * F_IN + k], W[(size_t)k * F_OUT + f], acc);
        float ref = elu_f(acc);
        float got = outd[(size_t)nn * F_OUT + f];
        if (!(fabsf(ref - got) <= 0.01f)) atomicOr(flag, 1);
    }
}

// ---------------------------------------------------------------------------
// Self MLP via bf16x3 MFMA v4: round-11 LDS-staged body (validated, 111 us)
// with __launch_bounds__(256,4): LDS 40 KB admits 4 blocks/CU, VGPR 80 < 128
// cap -> doubles residency vs (256,2) so barrier drains overlap other blocks'
// MFMA phases.
// ---------------------------------------------------------------------------
__global__ __launch_bounds__(256, 4) void self_mlp_mfma_kernel(
    const float* __restrict__ x,
    const unsigned short* __restrict__ W1Ahi, const unsigned short* __restrict__ W1Alo,
    const unsigned short* __restrict__ W2Ahi, const unsigned short* __restrict__ W2Alo,
    const float* __restrict__ b1, const float* __restrict__ b2,
    float* __restrict__ out)
{
    __shared__ unsigned short sW1hi[2048], sW1lo[2048];
    __shared__ unsigned short sW2hi[4096], sW2lo[4096];
    __shared__ unsigned short sHhi[4096], sHlo[4096];

    int tid = threadIdx.x, lane = tid & 63, w = tid >> 6;
    int l15 = lane & 15, g = lane >> 4;
    int node0 = blockIdx.x * 128;

    short8b xhi[2][2], xlo[2][2];
    #pragma unroll
    for (int nt = 0; nt < 2; ++nt) {
        int n = node0 + (2 * w + nt) * 16 + l15;
        if (n > N_NODES - 1) n = N_NODES - 1;
        #pragma unroll
        for (int ks = 0; ks < 2; ++ks) {
            const float* px = &x[(size_t)n * F_IN + ks * 32 + g * 8];
            float4 v0 = *reinterpret_cast<const float4*>(px);
            float4 v1 = *reinterpret_cast<const float4*>(px + 4);
            float vv[8] = {v0.x, v0.y, v0.z, v0.w, v1.x, v1.y, v1.z, v1.w};
            short8b h8, l8;
            #pragma unroll
            for (int i = 0; i < 8; ++i) {
                short hh, ll;
                split_bf(vv[i], hh, ll);
                h8[i] = hh;
                l8[i] = ll;
            }
            xhi[nt][ks] = h8;
            xlo[nt][ks] = l8;
        }
    }

    f32x4 acc[8][2];
    #pragma unroll
    for (int ft = 0; ft < 8; ++ft) {
        float4 bv = *reinterpret_cast<const float4*>(&b2[ft * 16 + g * 4]);
        #pragma unroll
        for (int nt = 0; nt < 2; ++nt) {
            acc[ft][nt][0] = bv.x; acc[ft][nt][1] = bv.y;
            acc[ft][nt][2] = bv.z; acc[ft][nt][3] = bv.w;
        }
    }

    for (int c = 0; c < 16; ++c) {
        __syncthreads();
        {
            const float4* s1h = reinterpret_cast<const float4*>(W1Ahi + (size_t)c * 2048);
            const float4* s1l = reinterpret_cast<const float4*>(W1Alo + (size_t)c * 2048);
            reinterpret_cast<float4*>(sW1hi)[tid] = s1h[tid];
            reinterpret_cast<float4*>(sW1lo)[tid] = s1l[tid];
            const float4* s2h = reinterpret_cast<const float4*>(W2Ahi + (size_t)c * 4096);
            const float4* s2l = reinterpret_cast<const float4*>(W2Alo + (size_t)c * 4096);
            reinterpret_cast<float4*>(sW2hi)[tid] = s2h[tid];
            reinterpret_cast<float4*>(sW2hi)[tid + 256] = s2h[tid + 256];
            reinterpret_cast<float4*>(sW2lo)[tid] = s2l[tid];
            reinterpret_cast<float4*>(sW2lo)[tid + 256] = s2l[tid + 256];
        }
        __syncthreads();

        #pragma unroll
        for (int ht = 0; ht < 2; ++ht) {
            #pragma unroll
            for (int nt = 0; nt < 2; ++nt) {
                f32x4 hacc;
                float4 b1v = *reinterpret_cast<const float4*>(&b1[c * 32 + ht * 16 + g * 4]);
                hacc[0] = b1v.x; hacc[1] = b1v.y; hacc[2] = b1v.z; hacc[3] = b1v.w;
                #pragma unroll
                for (int ks = 0; ks < 2; ++ks) {
                    short8b ah = *reinterpret_cast<const short8b*>(&sW1hi[((ht * 2 + ks) * 64 + lane) * 8]);
                    short8b al = *reinterpret_cast<const short8b*>(&sW1lo[((ht * 2 + ks) * 64 + lane) * 8]);
                    hacc = __builtin_amdgcn_mfma_f32_16x16x32_bf16(ah, xhi[nt][ks], hacc, 0, 0, 0);
                    hacc = __builtin_amdgcn_mfma_f32_16x16x32_bf16(ah, xlo[nt][ks], hacc, 0, 0, 0);
                    hacc = __builtin_amdgcn_mfma_f32_16x16x32_bf16(al, xhi[nt][ks], hacc, 0, 0, 0);
                }
                int nodeL = (2 * w + nt) * 16 + l15;
                short4b ph, pl;
                #pragma unroll
                for (int r = 0; r < 4; ++r) {
                    float hv = elu_f(hacc[r]);
                    short hh, ll;
                    split_bf(hv, hh, ll);
                    ph[r] = hh;
                    pl[r] = ll;
                }
                int byte = nodeL * 64 + (ht * 16 + g * 4) * 2;
                byte ^= (nodeL & 7) << 4;
                *reinterpret_cast<short4b*>(reinterpret_cast<char*>(sHhi) + byte) = ph;
                *reinterpret_cast<short4b*>(reinterpret_cast<char*>(sHlo) + byte) = pl;
            }
        }

        short8b bh[2], bl[2];
        #pragma unroll
        for (int nt = 0; nt < 2; ++nt) {
            int nodeL = (2 * w + nt) * 16 + l15;
            int byte = (nodeL * 64 + g * 16) ^ ((nodeL & 7) << 4);
            bh[nt] = *reinterpret_cast<const short8b*>(reinterpret_cast<const char*>(sHhi) + byte);
            bl[nt] = *reinterpret_cast<const short8b*>(reinterpret_cast<const char*>(sHlo) + byte);
        }
        #pragma unroll
        for (int ft = 0; ft < 8; ++ft) {
            short8b ah = *reinterpret_cast<const short8b*>(&sW2hi[(ft * 64 + lane) * 8]);
            short8b al = *reinterpret_cast<const short8b*>(&sW2lo[(ft * 64 + lane) * 8]);
            #pragma unroll
            for (int nt = 0; nt < 2; ++nt) {
                acc[ft][nt] = __builtin_amdgcn_mfma_f32_16x16x32_bf16(ah, bh[nt], acc[ft][nt], 0, 0, 0);
                acc[ft][nt] = __builtin_amdgcn_mfma_f32_16x16x32_bf16(ah, bl[nt], acc[ft][nt], 0, 0, 0);
                acc[ft][nt] = __builtin_amdgcn_mfma_f32_16x16x32_bf16(al, bh[nt], acc[ft][nt], 0, 0, 0);
            }
        }
    }

    #pragma unroll
    for (int ft = 0; ft < 8; ++ft) {
        #pragma unroll
        for (int nt = 0; nt < 2; ++nt) {
            int n = node0 + (2 * w + nt) * 16 + l15;
            if (n < N_NODES) {
                float4 o;
                o.x = elu_f(acc[ft][nt][0]);
                o.y = elu_f(acc[ft][nt][1]);
                o.z = elu_f(acc[ft][nt][2]);
                o.w = elu_f(acc[ft][nt][3]);
                *reinterpret_cast<float4*>(&out[(size_t)n * F_OUT + ft * 16 + g * 4]) = o;
            }
        }
    }
}

__global__ __launch_bounds__(256) void validate_kernel(
    const float* __restrict__ x,
    const float* __restrict__ W1, const float* __restrict__ b1,
    const float* __restrict__ W2, const float* __restrict__ b2,
    const float* __restrict__ out_self, int* __restrict__ flag)
{
    __shared__ float h[4][512];
    int tid = threadIdx.x;
    #pragma unroll
    for (int ii = 0; ii < 8; ++ii) {
        int gid = tid * 8 + ii;
        int n = gid >> 9, j = gid & 511;
        float acc = b1[j];
        for (int k = 0; k < F_IN; ++k)
            acc = fmaf(x[(size_t)n * F_IN + k], W1[(size_t)k * F_HID + j], acc);
        h[n][j] = elu_f(acc);
    }
    __syncthreads();
    #pragma unroll
    for (int ii = 0; ii < 2; ++ii) {
        int gid = tid * 2 + ii;
        int n = gid >> 7, f = gid & 127;
        float acc = b2[f];
        for (int j = 0; j < F_HID; ++j)
            acc = fmaf(h[n][j], W2[(size_t)j * F_OUT + f], acc);
        float ref = elu_f(acc);
        float got = out_self[(size_t)n * F_OUT + f];
        if (!(fabsf(ref - got) <= 0.01f)) atomicOr(flag, 1);
    }
}

// ---------------------------------------------------------------------------
// Flag-gated repairs.
// ---------------------------------------------------------------------------
__global__ __launch_bounds__(256) void gather_repair_kernel(
    const int* __restrict__ flag,
    const float* __restrict__ x,
    const int* __restrict__ rowptr, const int* __restrict__ col,
    float* __restrict__ agg)
{
    if (flag[0] == 0) return;
    int f = threadIdx.x & 63;
    for (int bb = blockIdx.x; bb < 25000; bb += gridDim.x) {
        int wid = bb * 4 + (threadIdx.x >> 6);
        if (wid >= N_NODES) continue;
        int beg = rowptr[wid];
        int end = rowptr[wid + 1];
        float acc = 0.0f;
        for (int e = beg; e < end; ++e)
            acc += x[(size_t)col[e] * F_IN + f];
        agg[(size_t)wid * F_IN + f] = acc / fmaxf((float)(end - beg), 1.0f);
    }
}

__global__ __launch_bounds__(256) void sage_lin_repair_kernel(
    const int* __restrict__ flag,
    const float* __restrict__ agg,
    const float* __restrict__ W, const float* __restrict__ b,
    float* __restrict__ out)
{
    if (flag[0] == 0) return;

    __shared__ float sW[F_IN][F_OUT];
    __shared__ float sA[16][68];

    int tid = threadIdx.x;
    int og = tid & 15;
    int nl = tid >> 4;

    for (int bb = blockIdx.x; bb < 6250; bb += gridDim.x) {
        int node0 = bb * 16;
        __syncthreads();
        #pragma unroll
        for (int it = 0; it < 8; ++it) {
            int i = tid + it * 256;
            int k = (i * 4) >> 7, ff = (i * 4) & 127;
            *reinterpret_cast<float4*>(&sW[k][ff]) =
                *reinterpret_cast<const float4*>(&W[(size_t)i * 4]);
        }
        {
            int nn = node0 + (tid >> 4), c4 = tid & 15;
            *reinterpret_cast<float4*>(&sA[tid >> 4][c4 * 4]) =
                *reinterpret_cast<const float4*>(&agg[(size_t)nn * F_IN + c4 * 4]);
        }
        __syncthreads();

        int n = node0 + nl;
        float acc[8];
        {
            float4 bl = *reinterpret_cast<const float4*>(&b[og * 4]);
            float4 bh = *reinterpret_cast<const float4*>(&b[64 + og * 4]);
            acc[0] = bl.x; acc[1] = bl.y; acc[2] = bl.z; acc[3] = bl.w;
            acc[4] = bh.x; acc[5] = bh.y; acc[6] = bh.z; acc[7] = bh.w;
        }
        for (int k = 0; k < F_IN; ++k) {
            float a = sA[nl][k];
            float4 w0 = *reinterpret_cast<const float4*>(&sW[k][og * 4]);
            float4 w1 = *reinterpret_cast<const float4*>(&sW[k][64 + og * 4]);
            acc[0] = fmaf(a, w0.x, acc[0]);
            acc[1] = fmaf(a, w0.y, acc[1]);
            acc[2] = fmaf(a, w0.z, acc[2]);
            acc[3] = fmaf(a, w0.w, acc[3]);
            acc[4] = fmaf(a, w1.x, acc[4]);
            acc[5] = fmaf(a, w1.y, acc[5]);
            acc[6] = fmaf(a, w1.z, acc[6]);
            acc[7] = fmaf(a, w1.w, acc[7]);
        }
        float4 o0 = make_float4(elu_f(acc[0]), elu_f(acc[1]), elu_f(acc[2]), elu_f(acc[3]));
        float4 o1 = make_float4(elu_f(acc[4]), elu_f(acc[5]), elu_f(acc[6]), elu_f(acc[7]));
        *reinterpret_cast<float4*>(&out[(size_t)n * F_OUT + og * 4]) = o0;
        *reinterpret_cast<float4*>(&out[(size_t)n * F_OUT + 64 + og * 4]) = o1;
    }
}

__global__ __launch_bounds__(256, 3) void self_mlp_repair_kernel(
    const int* __restrict__ flag,
    const float* __restrict__ x,
    const float* __restrict__ W1, const float* __restrict__ b1,
    const float* __restrict__ W2, const float* __restrict__ b2,
    float* __restrict__ out)
{
    if (flag[0] == 0) return;

    __shared__ float sXT[F_IN][128];
    __shared__ float sW1[F_IN][16];
    __shared__ float sHT[16][128];
    __shared__ float sW2[16][128];
    __shared__ float sb1[16];

    int tid = threadIdx.x;
    int node0 = blockIdx.x * 128;

    #pragma unroll
    for (int it = 0; it < 8; ++it) {
        int fid = tid + it * 256;
        int node = fid & 127, k4 = fid >> 7;
        int n = node0 + node;
        if (n > N_NODES - 1) n = N_NODES - 1;
        float4 v = *reinterpret_cast<const float4*>(&x[(size_t)n * F_IN + k4 * 4]);
        sXT[k4 * 4 + 0][node] = v.x;
        sXT[k4 * 4 + 1][node] = v.y;
        sXT[k4 * 4 + 2][node] = v.z;
        sXT[k4 * 4 + 3][node] = v.w;
    }

    int og = tid & 15;
    int ng = tid >> 4;
    int ng1 = tid & 31;
    int hg = tid >> 5;

    float acc[8][8];
    {
        float4 bl = *reinterpret_cast<const float4*>(&b2[og * 4]);
        float4 bh = *reinterpret_cast<const float4*>(&b2[64 + og * 4]);
        #pragma unroll
        for (int i = 0; i < 8; ++i) {
            acc[i][0] = bl.x; acc[i][1] = bl.y; acc[i][2] = bl.z; acc[i][3] = bl.w;
            acc[i][4] = bh.x; acc[i][5] = bh.y; acc[i][6] = bh.z; acc[i][7] = bh.w;
        }
    }

    for (int c = 0; c < 32; ++c) {
        int hid0 = c * 16;
        __syncthreads();

        {
            int k = tid >> 2, h4 = tid & 3;
            float4 v = *reinterpret_cast<const float4*>(&W1[(size_t)k * F_HID + hid0 + h4 * 4]);
            *reinterpret_cast<float4*>(&sW1[k][h4 * 4]) = v;
        }
        #pragma unroll
        for (int it = 0; it < 2; ++it) {
            int fid = tid + it * 256;
            int j = fid >> 5, f4 = fid & 31;
            float4 v = *reinterpret_cast<const float4*>(&W2[(size_t)(hid0 + j) * F_OUT + f4 * 4]);
            *reinterpret_cast<float4*>(&sW2[j][f4 * 4]) = v;
        }
        if (tid < 16) sb1[tid] = b1[hid0 + tid];
        __syncthreads();

        {
            float h0[4], h1[4];
            float bb0 = sb1[hg * 2], bb1 = sb1[hg * 2 + 1];
            #pragma unroll
            for (int i = 0; i < 4; ++i) { h0[i] = bb0; h1[i] = bb1; }
            #pragma unroll 8
            for (int k = 0; k < F_IN; ++k) {
                float4 a = *reinterpret_cast<const float4*>(&sXT[k][ng1 * 4]);
                float w0 = sW1[k][hg * 2];
                float w1 = sW1[k][hg * 2 + 1];
                h0[0] = fmaf(w0, a.x, h0[0]);
                h0[1] = fmaf(w0, a.y, h0[1]);
                h0[2] = fmaf(w0, a.z, h0[2]);
                h0[3] = fmaf(w0, a.w, h0[3]);
                h1[0] = fmaf(w1, a.x, h1[0]);
                h1[1] = fmaf(w1, a.y, h1[1]);
                h1[2] = fmaf(w1, a.z, h1[2]);
                h1[3] = fmaf(w1, a.w, h1[3]);
            }
            float4 o0 = make_float4(elu_f(h0[0]), elu_f(h0[1]), elu_f(h0[2]), elu_f(h0[3]));
            float4 o1 = make_float4(elu_f(h1[0]), elu_f(h1[1]), elu_f(h1[2]), elu_f(h1[3]));
            *reinterpret_cast<float4*>(&sHT[hg * 2][ng1 * 4]) = o0;
            *reinterpret_cast<float4*>(&sHT[hg * 2 + 1][ng1 * 4]) = o1;
        }
        __syncthreads();

        #pragma unroll 2
        for (int k = 0; k < 16; ++k) {
            float4 ha = *reinterpret_cast<const float4*>(&sHT[k][ng * 4]);
            float4 hb = *reinterpret_cast<const float4*>(&sHT[k][64 + ng * 4]);
            float4 wa = *reinterpret_cast<const float4*>(&sW2[k][og * 4]);
            float4 wb = *reinterpret_cast<const float4*>(&sW2[k][64 + og * 4]);
            float hv[8] = {ha.x, ha.y, ha.z, ha.w, hb.x, hb.y, hb.z, hb.w};
            float wv[8] = {wa.x, wa.y, wa.z, wa.w, wb.x, wb.y, wb.z, wb.w};
            #pragma unroll
            for (int i = 0; i < 8; ++i) {
                #pragma unroll
                for (int j = 0; j < 8; ++j) {
                    acc[i][j] = fmaf(hv[i], wv[j], acc[i][j]);
                }
            }
        }
    }

    #pragma unroll
    for (int i = 0; i < 8; ++i) {
        int n = node0 + (i < 4 ? ng * 4 + i : 64 + ng * 4 + (i - 4));
        if (n < N_NODES) {
            float4 o0 = make_float4(elu_f(acc[i][0]), elu_f(acc[i][1]),
                                    elu_f(acc[i][2]), elu_f(acc[i][3]));
            float4 o1 = make_float4(elu_f(acc[i][4]), elu_f(acc[i][5]),
                                    elu_f(acc[i][6]), elu_f(acc[i][7]));
            *reinterpret_cast<float4*>(&out[(size_t)n * F_OUT + og * 4]) = o0;
            *reinterpret_cast<float4*>(&out[(size_t)n * F_OUT + 64 + og * 4]) = o1;
        }
    }
}

// ---------------------------------------------------------------------------

extern "C" void kernel_launch(void* const* d_in, const int* in_sizes, int n_in,
                              void* d_out, int out_size, void* d_ws, size_t ws_size,
                              hipStream_t stream) {
    const float* x     = (const float*)d_in[0];
    const int*   ei    = (const int*)d_in[1];
    const float* W_in  = (const float*)d_in[2];
    const float* b_in  = (const float*)d_in[3];
    const float* W_out = (const float*)d_in[4];
    const float* b_out = (const float*)d_in[5];
    const float* W1    = (const float*)d_in[6];
    const float* b1    = (const float*)d_in[7];
    const float* W2    = (const float*)d_in[8];
    const float* b2    = (const float*)d_in[9];
    float* out = (float*)d_out;

    const int* src = ei;
    const int* dst = ei + N_EDGES;

    int* I = (int*)d_ws;
    int* rowptr_in  = I;                       // 100001
    int* rowptr_out = I + 100001;              // 100001
    int* col_in     = I + 200002;              // 1,000,000
    int* col_out    = I + 1200002;             // 1,000,000
    int* deg_in     = I + 2200002;             // 100,000  <- zeroed start
    int* deg_out    = I + 2300002;             // 100,000
    int* cur_in     = I + 2400002;             // 100,000  (repair scratch)
    int* cur_out    = I + 2500002;             // 100,000  <- zeroed end
    int* bsum_in    = I + 2600002;             // 128
    int* bsum_out   = I + 2600130;             // 128
    int* flagM      = I + 2600260;             // self MFMA
    int* flagS      = I + 2600261;             // sage MFMA
    int* flagC      = I + 2600262;             // CSR multisplit
    float* agg      = (float*)(I + 2600512);   // 100000*64 floats (25.6 MB)
    unsigned short* WF = (unsigned short*)(I + 9000512);
    unsigned short* W1Ahi  = WF;
    unsigned short* W1Alo  = WF + 32768;
    unsigned short* W2Ahi  = WF + 65536;
    unsigned short* W2Alo  = WF + 131072;
    unsigned short* WinAhi = WF + 196608;
    unsigned short* WinAlo = WF + 204800;
    unsigned short* WoutAhi= WF + 212992;
    unsigned short* WoutAlo= WF + 221184;      // ends at 229376 halfs
    unsigned short* xbf    = (unsigned short*)(I + 9120512);  // 6.4M halfs (12.8 MB)

    unsigned int* tmp_in  = (unsigned int*)agg;            // alias agg (dead until gather)
    unsigned int* tmp_out = (unsigned int*)agg + 1000000;
    int* bcur_in  = deg_in;                                // alias deg (dead after scans)
    int* bcur_out = deg_out;

    hipMemsetAsync(deg_in, 0, 400000 * sizeof(int), stream);
    hipMemsetAsync(flagM, 0, 3 * sizeof(int), stream);

    prep_w_kernel<<<56, 256, 0, stream>>>(W1, W2, W_in, W_out,
                                          W1Ahi, W1Alo, W2Ahi, W2Alo,
                                          WinAhi, WinAlo, WoutAhi, WoutAlo);
    prep_x_kernel<<<6250, 256, 0, stream>>>(x, xbf);

    const int eb = (N_EDGES + 255) / 256;      // 3907
    hist_kernel<<<eb, 256, 0, stream>>>(src, dst, deg_in, deg_out);

    const int sb = (N_NODES + 1023) / 1024;    // 98
    scan_block_kernel<<<sb, 256, 0, stream>>>(deg_in, rowptr_in, bsum_in, N_NODES);
    scan_block_kernel<<<sb, 256, 0, stream>>>(deg_out, rowptr_out, bsum_out, N_NODES);
    scan_top_kernel<<<1, 128, 0, stream>>>(bsum_in, sb);
    scan_top_kernel<<<1, 128, 0, stream>>>(bsum_out, sb);
    const int ab = (N_NODES + 255) / 256;      // 391
    scan_add_kernel<<<ab, 256, 0, stream>>>(rowptr_in, bsum_in, N_NODES, N_EDGES, bcur_in);
    scan_add_kernel<<<ab, 256, 0, stream>>>(rowptr_out, bsum_out, N_NODES, N_EDGES, bcur_out);

    const int p1b = (N_EDGES + 4095) / 4096;   // 245
    msplit_scatter_kernel<<<p1b, 512, 0, stream>>>(dst, src, bcur_in, tmp_in);
    msplit_scatter_kernel<<<p1b, 512, 0, stream>>>(src, dst, bcur_out, tmp_out);
    msplit_place_kernel<<<2 * NB, 256, 0, stream>>>(tmp_in, tmp_out,
                                                    rowptr_in, rowptr_out,
                                                    col_in, col_out, flagC);
    place_repair_kernel<<<eb, 256, 0, stream>>>(flagC, src, dst,
                                                rowptr_in, rowptr_out,
                                                cur_in, cur_out, col_in, col_out);

    const int gb = (N_NODES + 3) / 4;          // 25000
    const int mb = (N_NODES + 63) / 64;        // 1563
    float* out_in   = out;
    float* out_out  = out + (size_t)N_NODES * F_OUT;
    float* out_self = out + 2 * (size_t)N_NODES * F_OUT;

    gather_mean_kernel<<<gb, 256, 0, stream>>>(xbf, rowptr_in, col_in, agg);
    sage_lin_mfma_kernel<<<mb, 256, 0, stream>>>(agg, WinAhi, WinAlo, b_in, out_in);
    validate_sage_kernel<<<1, 256, 0, stream>>>(agg, W_in, b_in, out_in, flagS);

    gather_mean_kernel<<<gb, 256, 0, stream>>>(xbf, rowptr_out, col_out, agg);
    sage_lin_mfma_kernel<<<mb, 256, 0, stream>>>(agg, WoutAhi, WoutAlo, b_out, out_out);
    validate_sage_kernel<<<1, 256, 0, stream>>>(agg, W_out, b_out, out_out, flagS);

    self_mlp_mfma_kernel<<<782, 256, 0, stream>>>(x, W1Ahi, W1Alo, W2Ahi, W2Alo,
                                                  b1, b2, out_self);
    validate_kernel<<<1, 256, 0, stream>>>(x, W1, b1, W2, b2, out_self, flagM);

    self_mlp_repair_kernel<<<782, 256, 0, stream>>>(flagM, x, W1, b1, W2, b2, out_self);
    gather_repair_kernel<<<2048, 256, 0, stream>>>(flagS, x, rowptr_in, col_in, agg);
    sage_lin_repair_kernel<<<2048, 256, 0, stream>>>(flagS, agg, W_in, b_in, out_in);
    gather_repair_kernel<<<2048, 256, 0, stream>>>(flagS, x, rowptr_out, col_out, agg);
    sage_lin_repair_kernel<<<2048, 256, 0, stream>>>(flagS, agg, W_out, b_out, out_out);
}

// Round 16
// 466.939 us; speedup vs baseline: 1.1079x; 1.0037x over previous
//
#include <hip/hip_runtime.h>
#include <hip/hip_bf16.h>
#include <cstdint>
#include <cstddef>

#define N_NODES 100000
#define N_EDGES 1000000
#define F_IN 64
#define F_OUT 128
#define F_HID 512
#define NB 391          // buckets = ceil(100000 / 256)
#define BSH 8           // 256 nodes per bucket
#define SB 98           // scan blocks = ceil(100000/1024)
#define AB 391          // add blocks  = ceil(100000/256)
#define P1B 245         // msplit pass-1 blocks = ceil(1e6/4096)

typedef __attribute__((ext_vector_type(8))) short short8b;
typedef __attribute__((ext_vector_type(4))) short short4b;
typedef __attribute__((ext_vector_type(4))) float f32x4;

__device__ __forceinline__ float elu_f(float v) {
    return v > 0.0f ? v : __expf(v) - 1.0f;
}

__device__ __forceinline__ unsigned short f2bf(float v) {
    __hip_bfloat16 b = __float2bfloat16(v);
    return *reinterpret_cast<unsigned short*>(&b);
}
__device__ __forceinline__ float bf2f(unsigned short u) {
    unsigned int w = (unsigned int)u << 16;
    return __uint_as_float(w);
}
// Truncation-based hi/lo split: 4 VALU ops, |err| <= 2^-16 |v|.
__device__ __forceinline__ void split_bf(float v, short& hi, short& lo) {
    unsigned short h = (unsigned short)(__float_as_uint(v) >> 16);
    float r = v - bf2f(h);
    hi = (short)h;
    lo = (short)(unsigned short)(__float_as_uint(r) >> 16);
}

// ---------------------------------------------------------------------------
// Degree histogram.
// ---------------------------------------------------------------------------
__global__ __launch_bounds__(256) void hist_kernel(
    const int* __restrict__ src, const int* __restrict__ dst,
    int* __restrict__ deg_in, int* __restrict__ deg_out)
{
    int e = blockIdx.x * 256 + threadIdx.x;
    if (e < N_EDGES) {
        atomicAdd(&deg_in[dst[e]], 1);
        atomicAdd(&deg_out[src[e]], 1);
    }
}

// Fused dual-direction per-block scan (grid = 2*SB).
__global__ __launch_bounds__(256) void scan_block_kernel(
    const int* __restrict__ deg_in, const int* __restrict__ deg_out,
    int* __restrict__ rp_in, int* __restrict__ rp_out,
    int* __restrict__ bsum_in, int* __restrict__ bsum_out, int n)
{
    __shared__ int sSum[256];
    int b = blockIdx.x;
    const int* deg; int* rowptr; int* blockSums;
    if (b < SB) { deg = deg_in;  rowptr = rp_in;  blockSums = bsum_in; }
    else        { b -= SB; deg = deg_out; rowptr = rp_out; blockSums = bsum_out; }

    int tid = threadIdx.x;
    int base = b * 1024 + tid * 4;
    int v0 = (base + 0 < n) ? deg[base + 0] : 0;
    int v1 = (base + 1 < n) ? deg[base + 1] : 0;
    int v2 = (base + 2 < n) ? deg[base + 2] : 0;
    int v3 = (base + 3 < n) ? deg[base + 3] : 0;
    int s = v0 + v1 + v2 + v3;
    sSum[tid] = s;
    __syncthreads();
    int incl = s;
    for (int off = 1; off < 256; off <<= 1) {
        int t = (tid >= off) ? sSum[tid - off] : 0;
        __syncthreads();
        incl += t;
        sSum[tid] = incl;
        __syncthreads();
    }
    int exclT = incl - s;
    if (base + 0 < n) rowptr[base + 0] = exclT;
    if (base + 1 < n) rowptr[base + 1] = exclT + v0;
    if (base + 2 < n) rowptr[base + 2] = exclT + v0 + v1;
    if (base + 3 < n) rowptr[base + 3] = exclT + v0 + v1 + v2;
    if (tid == 255) blockSums[b] = incl;
}

// Fused dual-direction top scan (grid = 2).
__global__ __launch_bounds__(128) void scan_top_kernel(
    int* __restrict__ bs_in, int* __restrict__ bs_out, int nb)
{
    __shared__ int sh[128];
    int* blockSums = (blockIdx.x == 0) ? bs_in : bs_out;
    int tid = threadIdx.x;
    int v = (tid < nb) ? blockSums[tid] : 0;
    sh[tid] = v;
    __syncthreads();
    int incl = v;
    for (int off = 1; off < 128; off <<= 1) {
        int t = (tid >= off) ? sh[tid - off] : 0;
        __syncthreads();
        incl += t;
        sh[tid] = incl;
        __syncthreads();
    }
    if (tid < nb) blockSums[tid] = incl - v;
}

// Fused dual-direction scan_add + bcur seeding (grid = 2*AB).
__global__ __launch_bounds__(256) void scan_add_kernel(
    int* __restrict__ rp_in, int* __restrict__ rp_out,
    const int* __restrict__ bs_in, const int* __restrict__ bs_out,
    int* __restrict__ bcur_in, int* __restrict__ bcur_out, int n, int total)
{
    int b = blockIdx.x;
    int* rowptr; const int* blockSums; int* bcur;
    if (b < AB) { rowptr = rp_in;  blockSums = bs_in;  bcur = bcur_in; }
    else        { b -= AB; rowptr = rp_out; blockSums = bs_out; bcur = bcur_out; }
    int i = b * 256 + threadIdx.x;
    if (i < n) {
        int v = rowptr[i] + blockSums[i >> 10];
        rowptr[i] = v;
        if ((i & 255) == 0) bcur[i >> BSH] = v;
    }
    if (i == 0) rowptr[n] = total;
}

// ---------------------------------------------------------------------------
// Multisplit CSR placement. Fused dual-direction pass 1 (grid = 2*P1B).
// ---------------------------------------------------------------------------
__global__ __launch_bounds__(512) void msplit_scatter_kernel(
    const int* __restrict__ src, const int* __restrict__ dst,
    int* __restrict__ bcur_in, int* __restrict__ bcur_out,
    unsigned int* __restrict__ tmp_in, unsigned int* __restrict__ tmp_out)
{
    __shared__ int sCnt[NB];
    __shared__ int sBase[NB];
    int b = blockIdx.x;
    const int* keys; const int* vals; int* bcur; unsigned int* tmp;
    if (b < P1B) { keys = dst; vals = src; bcur = bcur_in;  tmp = tmp_in; }
    else         { b -= P1B; keys = src; vals = dst; bcur = bcur_out; tmp = tmp_out; }

    int tid = threadIdx.x;
    int tile0 = b * 4096;

    for (int i = tid; i < NB; i += 512) sCnt[i] = 0;
    __syncthreads();

    int key[8], rank[8];
    #pragma unroll
    for (int j = 0; j < 8; ++j) {
        int e = tile0 + j * 512 + tid;
        key[j] = -1;
        if (e < N_EDGES) {
            int k = keys[e];
            key[j] = k;
            rank[j] = atomicAdd(&sCnt[k >> BSH], 1);
        }
    }
    __syncthreads();
    for (int i = tid; i < NB; i += 512) sBase[i] = atomicAdd(&bcur[i], sCnt[i]);
    __syncthreads();
    #pragma unroll
    for (int j = 0; j < 8; ++j) {
        int e = tile0 + j * 512 + tid;
        if (e < N_EDGES) {
            int k = key[j];
            unsigned int rec = ((unsigned int)vals[e] << BSH) | (unsigned int)(k & 255);
            tmp[sBase[k >> BSH] + rank[j]] = rec;
        }
    }
}

__global__ __launch_bounds__(256) void msplit_place_kernel(
    const unsigned int* __restrict__ tmp_in, const unsigned int* __restrict__ tmp_out,
    const int* __restrict__ rp_in, const int* __restrict__ rp_out,
    int* __restrict__ col_in, int* __restrict__ col_out,
    int* __restrict__ flag)
{
    __shared__ int sCur[256];
    int b = blockIdx.x;
    const unsigned int* tmp; const int* rp; int* col;
    if (b < NB) { tmp = tmp_in;  rp = rp_in;  col = col_in; }
    else        { b -= NB; tmp = tmp_out; rp = rp_out; col = col_out; }

    int k0 = b << BSH;
    int kend = (k0 + 256 < N_NODES) ? k0 + 256 : N_NODES;
    int nk = kend - k0;
    int tid = threadIdx.x;
    if (tid < nk) sCur[tid] = rp[k0 + tid];
    __syncthreads();

    int beg = rp[k0], end = rp[kend];
    for (int e = beg + tid; e < end; e += 256) {
        unsigned int rec = tmp[e];
        int k8 = (int)(rec & 255u);
        int v  = (int)(rec >> BSH);
        if (k8 < nk) {
            int pos = atomicAdd(&sCur[k8], 1);
            col[pos] = v;
        } else {
            atomicOr(flag, 1);
        }
    }
    __syncthreads();
    if (tid < nk && sCur[tid] != rp[k0 + tid + 1]) atomicOr(flag, 1);
}

__global__ __launch_bounds__(256) void place_repair_kernel(
    const int* __restrict__ flag,
    const int* __restrict__ src, const int* __restrict__ dst,
    const int* __restrict__ rp_in, const int* __restrict__ rp_out,
    int* __restrict__ cur_in, int* __restrict__ cur_out,
    int* __restrict__ col_in, int* __restrict__ col_out)
{
    if (flag[0] == 0) return;
    int e = blockIdx.x * 256 + threadIdx.x;
    if (e >= N_EDGES) return;
    int s = src[e], d = dst[e];
    int p = rp_in[d] + atomicAdd(&cur_in[d], 1);
    col_in[p] = s;
    int q = rp_out[s] + atomicAdd(&cur_out[s], 1);
    col_out[q] = d;
}

// ---------------------------------------------------------------------------
// x -> bf16 copy. 4 elems/thread.
// ---------------------------------------------------------------------------
__global__ __launch_bounds__(256) void prep_x_kernel(
    const float* __restrict__ x, unsigned short* __restrict__ xbf)
{
    int i = blockIdx.x * 256 + threadIdx.x;
    int base = i * 4;
    if (base < N_NODES * F_IN) {
        float4 v = *reinterpret_cast<const float4*>(&x[base]);
        short4b o;
        o[0] = (short)f2bf(v.x);
        o[1] = (short)f2bf(v.y);
        o[2] = (short)f2bf(v.z);
        o[3] = (short)f2bf(v.w);
        *reinterpret_cast<short4b*>(&xbf[base]) = o;
    }
}

// ---------------------------------------------------------------------------
// Gather+mean v2: wide loads. Wave = 1 node; lane = (edge-slot g2, feat-quad
// l16). Each lane loads uint2 (4 bf16) -> 4 edges per VMEM instruction,
// 4-deep unrolled (16 edges in flight/wave). Cross-group reduce via shfl_xor.
// ---------------------------------------------------------------------------
__global__ __launch_bounds__(256) void gather_mean_kernel(
    const unsigned short* __restrict__ xbf,
    const int* __restrict__ rowptr, const int* __restrict__ col,
    float* __restrict__ agg)
{
    int wid = blockIdx.x * 4 + (threadIdx.x >> 6);
    int lane = threadIdx.x & 63;
    int g2 = lane >> 4;        // edge slot 0..3
    int l16 = lane & 15;       // feature quad 0..15
    if (wid >= N_NODES) return;
    int beg = rowptr[wid], end = rowptr[wid + 1];

    float4 acc = make_float4(0.0f, 0.0f, 0.0f, 0.0f);
    for (int e0 = beg; e0 < end; e0 += 16) {
        #pragma unroll
        for (int j = 0; j < 4; ++j) {
            int idx = e0 + j * 4 + g2;
            bool ok = idx < end;
            int c = col[ok ? idx : beg];
            uint2 v = *reinterpret_cast<const uint2*>(&xbf[(size_t)c * F_IN + l16 * 4]);
            if (ok) {
                acc.x += __uint_as_float(v.x << 16);
                acc.y += __uint_as_float(v.x & 0xffff0000u);
                acc.z += __uint_as_float(v.y << 16);
                acc.w += __uint_as_float(v.y & 0xffff0000u);
            }
        }
    }
    // Reduce across the 4 edge-slot groups (lanes ^16, ^32).
    acc.x += __shfl_xor(acc.x, 16);
    acc.y += __shfl_xor(acc.y, 16);
    acc.z += __shfl_xor(acc.z, 16);
    acc.w += __shfl_xor(acc.w, 16);
    acc.x += __shfl_xor(acc.x, 32);
    acc.y += __shfl_xor(acc.y, 32);
    acc.z += __shfl_xor(acc.z, 32);
    acc.w += __shfl_xor(acc.w, 32);

    if (g2 == 0) {
        float inv = 1.0f / fmaxf((float)(end - beg), 1.0f);
        float4 o = make_float4(acc.x * inv, acc.y * inv, acc.z * inv, acc.w * inv);
        *reinterpret_cast<float4*>(&agg[(size_t)wid * F_IN + l16 * 4]) = o;
    }
}

// ---------------------------------------------------------------------------
// Weight fragment prep (unchanged).
// ---------------------------------------------------------------------------
__global__ __launch_bounds__(256) void prep_w_kernel(
    const float* __restrict__ W1, const float* __restrict__ W2,
    const float* __restrict__ Win, const float* __restrict__ Wout,
    unsigned short* __restrict__ W1Ahi, unsigned short* __restrict__ W1Alo,
    unsigned short* __restrict__ W2Ahi, unsigned short* __restrict__ W2Alo,
    unsigned short* __restrict__ WinAhi, unsigned short* __restrict__ WinAlo,
    unsigned short* __restrict__ WoutAhi, unsigned short* __restrict__ WoutAlo)
{
    int t = blockIdx.x * 256 + threadIdx.x;
    int lane = t & 63;
    int l15 = lane & 15, g = lane >> 4;
    if (t < 4096) {
        int ht = (t >> 6) & 31, ks = t >> 11;
        int m = ht * 16 + l15;
        int k0 = ks * 32 + g * 8;
        size_t o = ((size_t)(ht * 2 + ks) * 64 + lane) * 8;
        #pragma unroll
        for (int i = 0; i < 8; ++i) {
            float v = W1[(size_t)(k0 + i) * F_HID + m];
            unsigned short hi = f2bf(v);
            W1Ahi[o + i] = hi;
            W1Alo[o + i] = f2bf(v - bf2f(hi));
        }
    } else if (t < 12288) {
        int u = t - 4096;
        int ft = (u >> 6) & 7, ks2 = u >> 9;
        int m = ft * 16 + l15;
        int k0 = ks2 * 32 + g * 8;
        size_t o = ((size_t)(ks2 * 8 + ft) * 64 + lane) * 8;
        #pragma unroll
        for (int i = 0; i < 8; ++i) {
            float v = W2[(size_t)(k0 + i) * F_OUT + m];
            unsigned short hi = f2bf(v);
            W2Ahi[o + i] = hi;
            W2Alo[o + i] = f2bf(v - bf2f(hi));
        }
    } else if (t < 14336) {
        int u = t - 12288;
        const float* W = (u < 1024) ? Win : Wout;
        unsigned short* Ahi = (u < 1024) ? WinAhi : WoutAhi;
        unsigned short* Alo = (u < 1024) ? WinAlo : WoutAlo;
        u &= 1023;
        int ft = (u >> 6) & 7, ks = u >> 9;
        int m = ft * 16 + l15;
        int k0 = ks * 32 + g * 8;
        size_t o = ((size_t)(ks * 8 + ft) * 64 + lane) * 8;
        #pragma unroll
        for (int i = 0; i < 8; ++i) {
            float v = W[(size_t)(k0 + i) * F_OUT + m];
            unsigned short hi = f2bf(v);
            Ahi[o + i] = hi;
            Alo[o + i] = f2bf(v - bf2f(hi));
        }
    }
}

// ---------------------------------------------------------------------------
// SAGE linear via bf16x3 MFMA (unchanged, validated).
// ---------------------------------------------------------------------------
__global__ __launch_bounds__(256) void sage_lin_mfma_kernel(
    const float* __restrict__ agg,
    const unsigned short* __restrict__ WAhi, const unsigned short* __restrict__ WAlo,
    const float* __restrict__ b, float* __restrict__ out)
{
    int tid = threadIdx.x, lane = tid & 63, w = tid >> 6;
    int l15 = lane & 15, g = lane >> 4;
    int n = blockIdx.x * 64 + w * 16 + l15;
    int nc = (n > N_NODES - 1) ? N_NODES - 1 : n;

    short8b bhf[2], blf[2];
    #pragma unroll
    for (int ks = 0; ks < 2; ++ks) {
        const float* pa = &agg[(size_t)nc * F_IN + ks * 32 + g * 8];
        float4 v0 = *reinterpret_cast<const float4*>(pa);
        float4 v1 = *reinterpret_cast<const float4*>(pa + 4);
        float vv[8] = {v0.x, v0.y, v0.z, v0.w, v1.x, v1.y, v1.z, v1.w};
        short8b h8, l8;
        #pragma unroll
        for (int i = 0; i < 8; ++i) {
            short hh, ll;
            split_bf(vv[i], hh, ll);
            h8[i] = hh;
            l8[i] = ll;
        }
        bhf[ks] = h8;
        blf[ks] = l8;
    }

    #pragma unroll
    for (int ft = 0; ft < 8; ++ft) {
        f32x4 acc;
        {
            float4 bv = *reinterpret_cast<const float4*>(&b[ft * 16 + g * 4]);
            acc[0] = bv.x; acc[1] = bv.y; acc[2] = bv.z; acc[3] = bv.w;
        }
        #pragma unroll
        for (int ks = 0; ks < 2; ++ks) {
            size_t o = ((size_t)(ks * 8 + ft) * 64 + lane) * 8;
            short8b ah = *reinterpret_cast<const short8b*>(&WAhi[o]);
            short8b al = *reinterpret_cast<const short8b*>(&WAlo[o]);
            acc = __builtin_amdgcn_mfma_f32_16x16x32_bf16(ah, bhf[ks], acc, 0, 0, 0);
            acc = __builtin_amdgcn_mfma_f32_16x16x32_bf16(ah, blf[ks], acc, 0, 0, 0);
            acc = __builtin_amdgcn_mfma_f32_16x16x32_bf16(al, bhf[ks], acc, 0, 0, 0);
        }
        if (n < N_NODES) {
            float4 o4;
            o4.x = elu_f(acc[0]);
            o4.y = elu_f(acc[1]);
            o4.z = elu_f(acc[2]);
            o4.w = elu_f(acc[3]);
            *reinterpret_cast<float4*>(&out[(size_t)n * F_OUT + ft * 16 + g * 4]) = o4;
        }
    }
}

__global__ __launch_bounds__(256) void validate_sage_kernel(
    const float* __restrict__ agg,
    const float* __restrict__ W, const float* __restrict__ b,
    const float* __restrict__ outd, int* __restrict__ flag)
{
    int tid = threadIdx.x;
    #pragma unroll
    for (int ii = 0; ii < 2; ++ii) {
        int gid = tid * 2 + ii;
        int nn = gid >> 7, f = gid & 127;
        float acc = b[f];
        for (int k = 0; k < F_IN; ++k)
            acc = fmaf(agg[(size_t)nn * F_IN + k], W[(size_t)k * F_OUT + f], acc);
        float ref = elu_f(acc);
        float got = outd[(size_t)nn * F_OUT + f];
        if (!(fabsf(ref - got) <= 0.01f)) atomicOr(flag, 1);
    }
}

// ---------------------------------------------------------------------------
// Self MLP via bf16x3 MFMA (round-14 validated: LDS-staged W, (256,4)).
// ---------------------------------------------------------------------------
__global__ __launch_bounds__(256, 4) void self_mlp_mfma_kernel(
    const float* __restrict__ x,
    const unsigned short* __restrict__ W1Ahi, const unsigned short* __restrict__ W1Alo,
    const unsigned short* __restrict__ W2Ahi, const unsigned short* __restrict__ W2Alo,
    const float* __restrict__ b1, const float* __restrict__ b2,
    float* __restrict__ out)
{
    __shared__ unsigned short sW1hi[2048], sW1lo[2048];
    __shared__ unsigned short sW2hi[4096], sW2lo[4096];
    __shared__ unsigned short sHhi[4096], sHlo[4096];

    int tid = threadIdx.x, lane = tid & 63, w = tid >> 6;
    int l15 = lane & 15, g = lane >> 4;
    int node0 = blockIdx.x * 128;

    short8b xhi[2][2], xlo[2][2];
    #pragma unroll
    for (int nt = 0; nt < 2; ++nt) {
        int n = node0 + (2 * w + nt) * 16 + l15;
        if (n > N_NODES - 1) n = N_NODES - 1;
        #pragma unroll
        for (int ks = 0; ks < 2; ++ks) {
            const float* px = &x[(size_t)n * F_IN + ks * 32 + g * 8];
            float4 v0 = *reinterpret_cast<const float4*>(px);
            float4 v1 = *reinterpret_cast<const float4*>(px + 4);
            float vv[8] = {v0.x, v0.y, v0.z, v0.w, v1.x, v1.y, v1.z, v1.w};
            short8b h8, l8;
            #pragma unroll
            for (int i = 0; i < 8; ++i) {
                short hh, ll;
                split_bf(vv[i], hh, ll);
                h8[i] = hh;
                l8[i] = ll;
            }
            xhi[nt][ks] = h8;
            xlo[nt][ks] = l8;
        }
    }

    f32x4 acc[8][2];
    #pragma unroll
    for (int ft = 0; ft < 8; ++ft) {
        float4 bv = *reinterpret_cast<const float4*>(&b2[ft * 16 + g * 4]);
        #pragma unroll
        for (int nt = 0; nt < 2; ++nt) {
            acc[ft][nt][0] = bv.x; acc[ft][nt][1] = bv.y;
            acc[ft][nt][2] = bv.z; acc[ft][nt][3] = bv.w;
        }
    }

    for (int c = 0; c < 16; ++c) {
        __syncthreads();
        {
            const float4* s1h = reinterpret_cast<const float4*>(W1Ahi + (size_t)c * 2048);
            const float4* s1l = reinterpret_cast<const float4*>(W1Alo + (size_t)c * 2048);
            reinterpret_cast<float4*>(sW1hi)[tid] = s1h[tid];
            reinterpret_cast<float4*>(sW1lo)[tid] = s1l[tid];
            const float4* s2h = reinterpret_cast<const float4*>(W2Ahi + (size_t)c * 4096);
            const float4* s2l = reinterpret_cast<const float4*>(W2Alo + (size_t)c * 4096);
            reinterpret_cast<float4*>(sW2hi)[tid] = s2h[tid];
            reinterpret_cast<float4*>(sW2hi)[tid + 256] = s2h[tid + 256];
            reinterpret_cast<float4*>(sW2lo)[tid] = s2l[tid];
            reinterpret_cast<float4*>(sW2lo)[tid + 256] = s2l[tid + 256];
        }
        __syncthreads();

        #pragma unroll
        for (int ht = 0; ht < 2; ++ht) {
            #pragma unroll
            for (int nt = 0; nt < 2; ++nt) {
                f32x4 hacc;
                float4 b1v = *reinterpret_cast<const float4*>(&b1[c * 32 + ht * 16 + g * 4]);
                hacc[0] = b1v.x; hacc[1] = b1v.y; hacc[2] = b1v.z; hacc[3] = b1v.w;
                #pragma unroll
                for (int ks = 0; ks < 2; ++ks) {
                    short8b ah = *reinterpret_cast<const short8b*>(&sW1hi[((ht * 2 + ks) * 64 + lane) * 8]);
                    short8b al = *reinterpret_cast<const short8b*>(&sW1lo[((ht * 2 + ks) * 64 + lane) * 8]);
                    hacc = __builtin_amdgcn_mfma_f32_16x16x32_bf16(ah, xhi[nt][ks], hacc, 0, 0, 0);
                    hacc = __builtin_amdgcn_mfma_f32_16x16x32_bf16(ah, xlo[nt][ks], hacc, 0, 0, 0);
                    hacc = __builtin_amdgcn_mfma_f32_16x16x32_bf16(al, xhi[nt][ks], hacc, 0, 0, 0);
                }
                int nodeL = (2 * w + nt) * 16 + l15;
                short4b ph, pl;
                #pragma unroll
                for (int r = 0; r < 4; ++r) {
                    float hv = elu_f(hacc[r]);
                    short hh, ll;
                    split_bf(hv, hh, ll);
                    ph[r] = hh;
                    pl[r] = ll;
                }
                int byte = nodeL * 64 + (ht * 16 + g * 4) * 2;
                byte ^= (nodeL & 7) << 4;
                *reinterpret_cast<short4b*>(reinterpret_cast<char*>(sHhi) + byte) = ph;
                *reinterpret_cast<short4b*>(reinterpret_cast<char*>(sHlo) + byte) = pl;
            }
        }

        short8b bh[2], bl[2];
        #pragma unroll
        for (int nt = 0; nt < 2; ++nt) {
            int nodeL = (2 * w + nt) * 16 + l15;
            int byte = (nodeL * 64 + g * 16) ^ ((nodeL & 7) << 4);
            bh[nt] = *reinterpret_cast<const short8b*>(reinterpret_cast<const char*>(sHhi) + byte);
            bl[nt] = *reinterpret_cast<const short8b*>(reinterpret_cast<const char*>(sHlo) + byte);
        }
        #pragma unroll
        for (int ft = 0; ft < 8; ++ft) {
            short8b ah = *reinterpret_cast<const short8b*>(&sW2hi[(ft * 64 + lane) * 8]);
            short8b al = *reinterpret_cast<const short8b*>(&sW2lo[(ft * 64 + lane) * 8]);
            #pragma unroll
            for (int nt = 0; nt < 2; ++nt) {
                acc[ft][nt] = __builtin_amdgcn_mfma_f32_16x16x32_bf16(ah, bh[nt], acc[ft][nt], 0, 0, 0);
                acc[ft][nt] = __builtin_amdgcn_mfma_f32_16x16x32_bf16(ah, bl[nt], acc[ft][nt], 0, 0, 0);
                acc[ft][nt] = __builtin_amdgcn_mfma_f32_16x16x32_bf16(al, bh[nt], acc[ft][nt], 0, 0, 0);
            }
        }
    }

    #pragma unroll
    for (int ft = 0; ft < 8; ++ft) {
        #pragma unroll
        for (int nt = 0; nt < 2; ++nt) {
            int n = node0 + (2 * w + nt) * 16 + l15;
            if (n < N_NODES) {
                float4 o;
                o.x = elu_f(acc[ft][nt][0]);
                o.y = elu_f(acc[ft][nt][1]);
                o.z = elu_f(acc[ft][nt][2]);
                o.w = elu_f(acc[ft][nt][3]);
                *reinterpret_cast<float4*>(&out[(size_t)n * F_OUT + ft * 16 + g * 4]) = o;
            }
        }
    }
}

__global__ __launch_bounds__(256) void validate_kernel(
    const float* __restrict__ x,
    const float* __restrict__ W1, const float* __restrict__ b1,
    const float* __restrict__ W2, const float* __restrict__ b2,
    const float* __restrict__ out_self, int* __restrict__ flag)
{
    __shared__ float h[4][512];
    int tid = threadIdx.x;
    #pragma unroll
    for (int ii = 0; ii < 8; ++ii) {
        int gid = tid * 8 + ii;
        int n = gid >> 9, j = gid & 511;
        float acc = b1[j];
        for (int k = 0; k < F_IN; ++k)
            acc = fmaf(x[(size_t)n * F_IN + k], W1[(size_t)k * F_HID + j], acc);
        h[n][j] = elu_f(acc);
    }
    __syncthreads();
    #pragma unroll
    for (int ii = 0; ii < 2; ++ii) {
        int gid = tid * 2 + ii;
        int n = gid >> 7, f = gid & 127;
        float acc = b2[f];
        for (int j = 0; j < F_HID; ++j)
            acc = fmaf(h[n][j], W2[(size_t)j * F_OUT + f], acc);
        float ref = elu_f(acc);
        float got = out_self[(size_t)n * F_OUT + f];
        if (!(fabsf(ref - got) <= 0.01f)) atomicOr(flag, 1);
    }
}

// ---------------------------------------------------------------------------
// Flag-gated repairs.
// ---------------------------------------------------------------------------
__global__ __launch_bounds__(256) void gather_repair_kernel(
    const int* __restrict__ flag,
    const float* __restrict__ x,
    const int* __restrict__ rowptr, const int* __restrict__ col,
    float* __restrict__ agg)
{
    if (flag[0] == 0) return;
    int f = threadIdx.x & 63;
    for (int bb = blockIdx.x; bb < 25000; bb += gridDim.x) {
        int wid = bb * 4 + (threadIdx.x >> 6);
        if (wid >= N_NODES) continue;
        int beg = rowptr[wid];
        int end = rowptr[wid + 1];
        float acc = 0.0f;
        for (int e = beg; e < end; ++e)
            acc += x[(size_t)col[e] * F_IN + f];
        agg[(size_t)wid * F_IN + f] = acc / fmaxf((float)(end - beg), 1.0f);
    }
}

__global__ __launch_bounds__(256) void sage_lin_repair_kernel(
    const int* __restrict__ flag,
    const float* __restrict__ agg,
    const float* __restrict__ W, const float* __restrict__ b,
    float* __restrict__ out)
{
    if (flag[0] == 0) return;

    __shared__ float sW[F_IN][F_OUT];
    __shared__ float sA[16][68];

    int tid = threadIdx.x;
    int og = tid & 15;
    int nl = tid >> 4;

    for (int bb = blockIdx.x; bb < 6250; bb += gridDim.x) {
        int node0 = bb * 16;
        __syncthreads();
        #pragma unroll
        for (int it = 0; it < 8; ++it) {
            int i = tid + it * 256;
            int k = (i * 4) >> 7, ff = (i * 4) & 127;
            *reinterpret_cast<float4*>(&sW[k][ff]) =
                *reinterpret_cast<const float4*>(&W[(size_t)i * 4]);
        }
        {
            int nn = node0 + (tid >> 4), c4 = tid & 15;
            *reinterpret_cast<float4*>(&sA[tid >> 4][c4 * 4]) =
                *reinterpret_cast<const float4*>(&agg[(size_t)nn * F_IN + c4 * 4]);
        }
        __syncthreads();

        int n = node0 + nl;
        float acc[8];
        {
            float4 bl = *reinterpret_cast<const float4*>(&b[og * 4]);
            float4 bh = *reinterpret_cast<const float4*>(&b[64 + og * 4]);
            acc[0] = bl.x; acc[1] = bl.y; acc[2] = bl.z; acc[3] = bl.w;
            acc[4] = bh.x; acc[5] = bh.y; acc[6] = bh.z; acc[7] = bh.w;
        }
        for (int k = 0; k < F_IN; ++k) {
            float a = sA[nl][k];
            float4 w0 = *reinterpret_cast<const float4*>(&sW[k][og * 4]);
            float4 w1 = *reinterpret_cast<const float4*>(&sW[k][64 + og * 4]);
            acc[0] = fmaf(a, w0.x, acc[0]);
            acc[1] = fmaf(a, w0.y, acc[1]);
            acc[2] = fmaf(a, w0.z, acc[2]);
            acc[3] = fmaf(a, w0.w, acc[3]);
            acc[4] = fmaf(a, w1.x, acc[4]);
            acc[5] = fmaf(a, w1.y, acc[5]);
            acc[6] = fmaf(a, w1.z, acc[6]);
            acc[7] = fmaf(a, w1.w, acc[7]);
        }
        float4 o0 = make_float4(elu_f(acc[0]), elu_f(acc[1]), elu_f(acc[2]), elu_f(acc[3]));
        float4 o1 = make_float4(elu_f(acc[4]), elu_f(acc[5]), elu_f(acc[6]), elu_f(acc[7]));
        *reinterpret_cast<float4*>(&out[(size_t)n * F_OUT + og * 4]) = o0;
        *reinterpret_cast<float4*>(&out[(size_t)n * F_OUT + 64 + og * 4]) = o1;
    }
}

__global__ __launch_bounds__(256, 3) void self_mlp_repair_kernel(
    const int* __restrict__ flag,
    const float* __restrict__ x,
    const float* __restrict__ W1, const float* __restrict__ b1,
    const float* __restrict__ W2, const float* __restrict__ b2,
    float* __restrict__ out)
{
    if (flag[0] == 0) return;

    __shared__ float sXT[F_IN][128];
    __shared__ float sW1[F_IN][16];
    __shared__ float sHT[16][128];
    __shared__ float sW2[16][128];
    __shared__ float sb1[16];

    int tid = threadIdx.x;
    int node0 = blockIdx.x * 128;

    #pragma unroll
    for (int it = 0; it < 8; ++it) {
        int fid = tid + it * 256;
        int node = fid & 127, k4 = fid >> 7;
        int n = node0 + node;
        if (n > N_NODES - 1) n = N_NODES - 1;
        float4 v = *reinterpret_cast<const float4*>(&x[(size_t)n * F_IN + k4 * 4]);
        sXT[k4 * 4 + 0][node] = v.x;
        sXT[k4 * 4 + 1][node] = v.y;
        sXT[k4 * 4 + 2][node] = v.z;
        sXT[k4 * 4 + 3][node] = v.w;
    }

    int og = tid & 15;
    int ng = tid >> 4;
    int ng1 = tid & 31;
    int hg = tid >> 5;

    float acc[8][8];
    {
        float4 bl = *reinterpret_cast<const float4*>(&b2[og * 4]);
        float4 bh = *reinterpret_cast<const float4*>(&b2[64 + og * 4]);
        #pragma unroll
        for (int i = 0; i < 8; ++i) {
            acc[i][0] = bl.x; acc[i][1] = bl.y; acc[i][2] = bl.z; acc[i][3] = bl.w;
            acc[i][4] = bh.x; acc[i][5] = bh.y; acc[i][6] = bh.z; acc[i][7] = bh.w;
        }
    }

    for (int c = 0; c < 32; ++c) {
        int hid0 = c * 16;
        __syncthreads();

        {
            int k = tid >> 2, h4 = tid & 3;
            float4 v = *reinterpret_cast<const float4*>(&W1[(size_t)k * F_HID + hid0 + h4 * 4]);
            *reinterpret_cast<float4*>(&sW1[k][h4 * 4]) = v;
        }
        #pragma unroll
        for (int it = 0; it < 2; ++it) {
            int fid = tid + it * 256;
            int j = fid >> 5, f4 = fid & 31;
            float4 v = *reinterpret_cast<const float4*>(&W2[(size_t)(hid0 + j) * F_OUT + f4 * 4]);
            *reinterpret_cast<float4*>(&sW2[j][f4 * 4]) = v;
        }
        if (tid < 16) sb1[tid] = b1[hid0 + tid];
        __syncthreads();

        {
            float h0[4], h1[4];
            float bb0 = sb1[hg * 2], bb1 = sb1[hg * 2 + 1];
            #pragma unroll
            for (int i = 0; i < 4; ++i) { h0[i] = bb0; h1[i] = bb1; }
            #pragma unroll 8
            for (int k = 0; k < F_IN; ++k) {
                float4 a = *reinterpret_cast<const float4*>(&sXT[k][ng1 * 4]);
                float w0 = sW1[k][hg * 2];
                float w1 = sW1[k][hg * 2 + 1];
                h0[0] = fmaf(w0, a.x, h0[0]);
                h0[1] = fmaf(w0, a.y, h0[1]);
                h0[2] = fmaf(w0, a.z, h0[2]);
                h0[3] = fmaf(w0, a.w, h0[3]);
                h1[0] = fmaf(w1, a.x, h1[0]);
                h1[1] = fmaf(w1, a.y, h1[1]);
                h1[2] = fmaf(w1, a.z, h1[2]);
                h1[3] = fmaf(w1, a.w, h1[3]);
            }
            float4 o0 = make_float4(elu_f(h0[0]), elu_f(h0[1]), elu_f(h0[2]), elu_f(h0[3]));
            float4 o1 = make_float4(elu_f(h1[0]), elu_f(h1[1]), elu_f(h1[2]), elu_f(h1[3]));
            *reinterpret_cast<float4*>(&sHT[hg * 2][ng1 * 4]) = o0;
            *reinterpret_cast<float4*>(&sHT[hg * 2 + 1][ng1 * 4]) = o1;
        }
        __syncthreads();

        #pragma unroll 2
        for (int k = 0; k < 16; ++k) {
            float4 ha = *reinterpret_cast<const float4*>(&sHT[k][ng * 4]);
            float4 hb = *reinterpret_cast<const float4*>(&sHT[k][64 + ng * 4]);
            float4 wa = *reinterpret_cast<const float4*>(&sW2[k][og * 4]);
            float4 wb = *reinterpret_cast<const float4*>(&sW2[k][64 + og * 4]);
            float hv[8] = {ha.x, ha.y, ha.z, ha.w, hb.x, hb.y, hb.z, hb.w};
            float wv[8] = {wa.x, wa.y, wa.z, wa.w, wb.x, wb.y, wb.z, wb.w};
            #pragma unroll
            for (int i = 0; i < 8; ++i) {
                #pragma unroll
                for (int j = 0; j < 8; ++j) {
                    acc[i][j] = fmaf(hv[i], wv[j], acc[i][j]);
                }
            }
        }
    }

    #pragma unroll
    for (int i = 0; i < 8; ++i) {
        int n = node0 + (i < 4 ? ng * 4 + i : 64 + ng * 4 + (i - 4));
        if (n < N_NODES) {
            float4 o0 = make_float4(elu_f(acc[i][0]), elu_f(acc[i][1]),
                                    elu_f(acc[i][2]), elu_f(acc[i][3]));
            float4 o1 = make_float4(elu_f(acc[i][4]), elu_f(acc[i][5]),
                                    elu_f(acc[i][6]), elu_f(acc[i][7]));
            *reinterpret_cast<float4*>(&out[(size_t)n * F_OUT + og * 4]) = o0;
            *reinterpret_cast<float4*>(&out[(size_t)n * F_OUT + 64 + og * 4]) = o1;
        }
    }
}

// ---------------------------------------------------------------------------

extern "C" void kernel_launch(void* const* d_in, const int* in_sizes, int n_in,
                              void* d_out, int out_size, void* d_ws, size_t ws_size,
                              hipStream_t stream) {
    const float* x     = (const float*)d_in[0];
    const int*   ei    = (const int*)d_in[1];
    const float* W_in  = (const float*)d_in[2];
    const float* b_in  = (const float*)d_in[3];
    const float* W_out = (const float*)d_in[4];
    const float* b_out = (const float*)d_in[5];
    const float* W1    = (const float*)d_in[6];
    const float* b1    = (const float*)d_in[7];
    const float* W2    = (const float*)d_in[8];
    const float* b2    = (const float*)d_in[9];
    float* out = (float*)d_out;

    const int* src = ei;
    const int* dst = ei + N_EDGES;

    int* I = (int*)d_ws;
    int* rowptr_in  = I;                       // 100001
    int* rowptr_out = I + 100001;              // 100001
    int* col_in     = I + 200002;              // 1,000,000
    int* col_out    = I + 1200002;             // 1,000,000
    int* deg_in     = I + 2200002;             // 100,000  <- zeroed start
    int* deg_out    = I + 2300002;             // 100,000
    int* cur_in     = I + 2400002;             // 100,000  (repair scratch)
    int* cur_out    = I + 2500002;             // 100,000  <- zeroed end
    int* bsum_in    = I + 2600002;             // 128
    int* bsum_out   = I + 2600130;             // 128
    int* flagM      = I + 2600260;             // self MFMA
    int* flagS      = I + 2600261;             // sage MFMA
    int* flagC      = I + 2600262;             // CSR multisplit
    float* agg      = (float*)(I + 2600512);   // 100000*64 floats (25.6 MB)
    unsigned short* WF = (unsigned short*)(I + 9000512);
    unsigned short* W1Ahi  = WF;
    unsigned short* W1Alo  = WF + 32768;
    unsigned short* W2Ahi  = WF + 65536;
    unsigned short* W2Alo  = WF + 131072;
    unsigned short* WinAhi = WF + 196608;
    unsigned short* WinAlo = WF + 204800;
    unsigned short* WoutAhi= WF + 212992;
    unsigned short* WoutAlo= WF + 221184;      // ends at 229376 halfs
    unsigned short* xbf    = (unsigned short*)(I + 9120512);  // 6.4M halfs (12.8 MB)

    unsigned int* tmp_in  = (unsigned int*)agg;            // alias agg (dead until gather)
    unsigned int* tmp_out = (unsigned int*)agg + 1000000;
    int* bcur_in  = deg_in;                                // alias deg (dead after scans)
    int* bcur_out = deg_out;

    hipMemsetAsync(deg_in, 0, 400000 * sizeof(int), stream);
    hipMemsetAsync(flagM, 0, 3 * sizeof(int), stream);

    prep_w_kernel<<<56, 256, 0, stream>>>(W1, W2, W_in, W_out,
                                          W1Ahi, W1Alo, W2Ahi, W2Alo,
                                          WinAhi, WinAlo, WoutAhi, WoutAlo);
    prep_x_kernel<<<6250, 256, 0, stream>>>(x, xbf);

    const int eb = (N_EDGES + 255) / 256;      // 3907
    hist_kernel<<<eb, 256, 0, stream>>>(src, dst, deg_in, deg_out);

    // Fused dual-direction scans.
    scan_block_kernel<<<2 * SB, 256, 0, stream>>>(deg_in, deg_out,
                                                  rowptr_in, rowptr_out,
                                                  bsum_in, bsum_out, N_NODES);
    scan_top_kernel<<<2, 128, 0, stream>>>(bsum_in, bsum_out, SB);
    scan_add_kernel<<<2 * AB, 256, 0, stream>>>(rowptr_in, rowptr_out,
                                                bsum_in, bsum_out,
                                                bcur_in, bcur_out,
                                                N_NODES, N_EDGES);

    // Fused dual-direction multisplit pass 1, then pass 2.
    msplit_scatter_kernel<<<2 * P1B, 512, 0, stream>>>(src, dst,
                                                       bcur_in, bcur_out,
                                                       tmp_in, tmp_out);
    msplit_place_kernel<<<2 * NB, 256, 0, stream>>>(tmp_in, tmp_out,
                                                    rowptr_in, rowptr_out,
                                                    col_in, col_out, flagC);
    place_repair_kernel<<<eb, 256, 0, stream>>>(flagC, src, dst,
                                                rowptr_in, rowptr_out,
                                                cur_in, cur_out, col_in, col_out);

    const int gb = (N_NODES + 3) / 4;          // 25000
    const int mb = (N_NODES + 63) / 64;        // 1563
    float* out_in   = out;
    float* out_out  = out + (size_t)N_NODES * F_OUT;
    float* out_self = out + 2 * (size_t)N_NODES * F_OUT;

    gather_mean_kernel<<<gb, 256, 0, stream>>>(xbf, rowptr_in, col_in, agg);
    sage_lin_mfma_kernel<<<mb, 256, 0, stream>>>(agg, WinAhi, WinAlo, b_in, out_in);
    validate_sage_kernel<<<1, 256, 0, stream>>>(agg, W_in, b_in, out_in, flagS);

    gather_mean_kernel<<<gb, 256, 0, stream>>>(xbf, rowptr_out, col_out, agg);
    sage_lin_mfma_kernel<<<mb, 256, 0, stream>>>(agg, WoutAhi, WoutAlo, b_out, out_out);
    validate_sage_kernel<<<1, 256, 0, stream>>>(agg, W_out, b_out, out_out, flagS);

    self_mlp_mfma_kernel<<<782, 256, 0, stream>>>(x, W1Ahi, W1Alo, W2Ahi, W2Alo,
                                                  b1, b2, out_self);
    validate_kernel<<<1, 256, 0, stream>>>(x, W1, b1, W2, b2, out_self, flagM);

    self_mlp_repair_kernel<<<782, 256, 0, stream>>>(flagM, x, W1, b1, W2, b2, out_self);
    gather_repair_kernel<<<2048, 256, 0, stream>>>(flagS, x, rowptr_in, col_in, agg);
    sage_lin_repair_kernel<<<2048, 256, 0, stream>>>(flagS, agg, W_in, b_in, out_in);
    gather_repair_kernel<<<2048, 256, 0, stream>>>(flagS, x, rowptr_out, col_out, agg);
    sage_lin_repair_kernel<<<2048, 256, 0, stream>>>(flagS, agg, W_out, b_out, out_out);
}

// Round 18
// 384.440 us; speedup vs baseline: 1.3456x; 1.2146x over previous
//
#include <hip/hip_runtime.h>
#include <hip/hip_bf16.h>
#include <cstdint>
#include <cstddef>

#define N_NODES 100000
#define N_EDGES 1000000
#define F_IN 64
#define F_OUT 128
#define F_HID 512
#define NB 391          // buckets = ceil(100000 / 256)
#define BSH 8           // 256 nodes per bucket
#define SB 98           // scan blocks = ceil(100000/1024)
#define AB 391          // add blocks  = ceil(100000/256)
#define P1B 245         // msplit pass-1 blocks = ceil(1e6/4096)

typedef __attribute__((ext_vector_type(8))) short short8b;
typedef __attribute__((ext_vector_type(4))) short short4b;
typedef __attribute__((ext_vector_type(4))) float f32x4;

__device__ __forceinline__ float elu_f(float v) {
    return v > 0.0f ? v : __expf(v) - 1.0f;
}

__device__ __forceinline__ unsigned short f2bf(float v) {
    __hip_bfloat16 b = __float2bfloat16(v);
    return *reinterpret_cast<unsigned short*>(&b);
}
__device__ __forceinline__ float bf2f(unsigned short u) {
    unsigned int w = (unsigned int)u << 16;
    return __uint_as_float(w);
}
// Truncation-based hi/lo split: 4 VALU ops, |err| <= 2^-16 |v|.
__device__ __forceinline__ void split_bf(float v, short& hi, short& lo) {
    unsigned short h = (unsigned short)(__float_as_uint(v) >> 16);
    float r = v - bf2f(h);
    hi = (short)h;
    lo = (short)(unsigned short)(__float_as_uint(r) >> 16);
}

// ---------------------------------------------------------------------------
// Degree histogram.
// ---------------------------------------------------------------------------
__global__ __launch_bounds__(256) void hist_kernel(
    const int* __restrict__ src, const int* __restrict__ dst,
    int* __restrict__ deg_in, int* __restrict__ deg_out)
{
    int e = blockIdx.x * 256 + threadIdx.x;
    if (e < N_EDGES) {
        atomicAdd(&deg_in[dst[e]], 1);
        atomicAdd(&deg_out[src[e]], 1);
    }
}

// Fused dual-direction per-block scan (grid = 2*SB).
__global__ __launch_bounds__(256) void scan_block_kernel(
    const int* __restrict__ deg_in, const int* __restrict__ deg_out,
    int* __restrict__ rp_in, int* __restrict__ rp_out,
    int* __restrict__ bsum_in, int* __restrict__ bsum_out, int n)
{
    __shared__ int sSum[256];
    int b = blockIdx.x;
    const int* deg; int* rowptr; int* blockSums;
    if (b < SB) { deg = deg_in;  rowptr = rp_in;  blockSums = bsum_in; }
    else        { b -= SB; deg = deg_out; rowptr = rp_out; blockSums = bsum_out; }

    int tid = threadIdx.x;
    int base = b * 1024 + tid * 4;
    int v0 = (base + 0 < n) ? deg[base + 0] : 0;
    int v1 = (base + 1 < n) ? deg[base + 1] : 0;
    int v2 = (base + 2 < n) ? deg[base + 2] : 0;
    int v3 = (base + 3 < n) ? deg[base + 3] : 0;
    int s = v0 + v1 + v2 + v3;
    sSum[tid] = s;
    __syncthreads();
    int incl = s;
    for (int off = 1; off < 256; off <<= 1) {
        int t = (tid >= off) ? sSum[tid - off] : 0;
        __syncthreads();
        incl += t;
        sSum[tid] = incl;
        __syncthreads();
    }
    int exclT = incl - s;
    if (base + 0 < n) rowptr[base + 0] = exclT;
    if (base + 1 < n) rowptr[base + 1] = exclT + v0;
    if (base + 2 < n) rowptr[base + 2] = exclT + v0 + v1;
    if (base + 3 < n) rowptr[base + 3] = exclT + v0 + v1 + v2;
    if (tid == 255) blockSums[b] = incl;
}

// Fused dual-direction top scan (grid = 2).
__global__ __launch_bounds__(128) void scan_top_kernel(
    int* __restrict__ bs_in, int* __restrict__ bs_out, int nb)
{
    __shared__ int sh[128];
    int* blockSums = (blockIdx.x == 0) ? bs_in : bs_out;
    int tid = threadIdx.x;
    int v = (tid < nb) ? blockSums[tid] : 0;
    sh[tid] = v;
    __syncthreads();
    int incl = v;
    for (int off = 1; off < 128; off <<= 1) {
        int t = (tid >= off) ? sh[tid - off] : 0;
        __syncthreads();
        incl += t;
        sh[tid] = incl;
        __syncthreads();
    }
    if (tid < nb) blockSums[tid] = incl - v;
}

// Fused dual-direction scan_add + bcur seeding (grid = 2*AB).
__global__ __launch_bounds__(256) void scan_add_kernel(
    int* __restrict__ rp_in, int* __restrict__ rp_out,
    const int* __restrict__ bs_in, const int* __restrict__ bs_out,
    int* __restrict__ bcur_in, int* __restrict__ bcur_out, int n, int total)
{
    int b = blockIdx.x;
    int* rowptr; const int* blockSums; int* bcur;
    if (b < AB) { rowptr = rp_in;  blockSums = bs_in;  bcur = bcur_in; }
    else        { b -= AB; rowptr = rp_out; blockSums = bs_out; bcur = bcur_out; }
    int i = b * 256 + threadIdx.x;
    if (i < n) {
        int v = rowptr[i] + blockSums[i >> 10];
        rowptr[i] = v;
        if ((i & 255) == 0) bcur[i >> BSH] = v;
    }
    if (i == 0) rowptr[n] = total;
}

// ---------------------------------------------------------------------------
// Multisplit CSR placement. Fused dual-direction pass 1 (grid = 2*P1B).
// ---------------------------------------------------------------------------
__global__ __launch_bounds__(512) void msplit_scatter_kernel(
    const int* __restrict__ src, const int* __restrict__ dst,
    int* __restrict__ bcur_in, int* __restrict__ bcur_out,
    unsigned int* __restrict__ tmp_in, unsigned int* __restrict__ tmp_out)
{
    __shared__ int sCnt[NB];
    __shared__ int sBase[NB];
    int b = blockIdx.x;
    const int* keys; const int* vals; int* bcur; unsigned int* tmp;
    if (b < P1B) { keys = dst; vals = src; bcur = bcur_in;  tmp = tmp_in; }
    else         { b -= P1B; keys = src; vals = dst; bcur = bcur_out; tmp = tmp_out; }

    int tid = threadIdx.x;
    int tile0 = b * 4096;

    for (int i = tid; i < NB; i += 512) sCnt[i] = 0;
    __syncthreads();

    int key[8], rank[8];
    #pragma unroll
    for (int j = 0; j < 8; ++j) {
        int e = tile0 + j * 512 + tid;
        key[j] = -1;
        if (e < N_EDGES) {
            int k = keys[e];
            key[j] = k;
            rank[j] = atomicAdd(&sCnt[k >> BSH], 1);
        }
    }
    __syncthreads();
    for (int i = tid; i < NB; i += 512) sBase[i] = atomicAdd(&bcur[i], sCnt[i]);
    __syncthreads();
    #pragma unroll
    for (int j = 0; j < 8; ++j) {
        int e = tile0 + j * 512 + tid;
        if (e < N_EDGES) {
            int k = key[j];
            unsigned int rec = ((unsigned int)vals[e] << BSH) | (unsigned int)(k & 255);
            tmp[sBase[k >> BSH] + rank[j]] = rec;
        }
    }
}

__global__ __launch_bounds__(256) void msplit_place_kernel(
    const unsigned int* __restrict__ tmp_in, const unsigned int* __restrict__ tmp_out,
    const int* __restrict__ rp_in, const int* __restrict__ rp_out,
    int* __restrict__ col_in, int* __restrict__ col_out,
    int* __restrict__ flag)
{
    __shared__ int sCur[256];
    int b = blockIdx.x;
    const unsigned int* tmp; const int* rp; int* col;
    if (b < NB) { tmp = tmp_in;  rp = rp_in;  col = col_in; }
    else        { b -= NB; tmp = tmp_out; rp = rp_out; col = col_out; }

    int k0 = b << BSH;
    int kend = (k0 + 256 < N_NODES) ? k0 + 256 : N_NODES;
    int nk = kend - k0;
    int tid = threadIdx.x;
    if (tid < nk) sCur[tid] = rp[k0 + tid];
    __syncthreads();

    int beg = rp[k0], end = rp[kend];
    for (int e = beg + tid; e < end; e += 256) {
        unsigned int rec = tmp[e];
        int k8 = (int)(rec & 255u);
        int v  = (int)(rec >> BSH);
        if (k8 < nk) {
            int pos = atomicAdd(&sCur[k8], 1);
            col[pos] = v;
        } else {
            atomicOr(flag, 1);
        }
    }
    __syncthreads();
    if (tid < nk && sCur[tid] != rp[k0 + tid + 1]) atomicOr(flag, 1);
}

__global__ __launch_bounds__(256) void place_repair_kernel(
    const int* __restrict__ flag,
    const int* __restrict__ src, const int* __restrict__ dst,
    const int* __restrict__ rp_in, const int* __restrict__ rp_out,
    int* __restrict__ cur_in, int* __restrict__ cur_out,
    int* __restrict__ col_in, int* __restrict__ col_out)
{
    if (flag[0] == 0) return;
    int e = blockIdx.x * 256 + threadIdx.x;
    if (e >= N_EDGES) return;
    int s = src[e], d = dst[e];
    int p = rp_in[d] + atomicAdd(&cur_in[d], 1);
    col_in[p] = s;
    int q = rp_out[s] + atomicAdd(&cur_out[s], 1);
    col_out[q] = d;
}

// ---------------------------------------------------------------------------
// x -> bf16 copy. 4 elems/thread.
// ---------------------------------------------------------------------------
__global__ __launch_bounds__(256) void prep_x_kernel(
    const float* __restrict__ x, unsigned short* __restrict__ xbf)
{
    int i = blockIdx.x * 256 + threadIdx.x;
    int base = i * 4;
    if (base < N_NODES * F_IN) {
        float4 v = *reinterpret_cast<const float4*>(&x[base]);
        short4b o;
        o[0] = (short)f2bf(v.x);
        o[1] = (short)f2bf(v.y);
        o[2] = (short)f2bf(v.z);
        o[3] = (short)f2bf(v.w);
        *reinterpret_cast<short4b*>(&xbf[base]) = o;
    }
}

// ---------------------------------------------------------------------------
// Gather+mean v2 (round-16 validated): wide uint2 loads + shfl_xor reduce.
// ---------------------------------------------------------------------------
__global__ __launch_bounds__(256) void gather_mean_kernel(
    const unsigned short* __restrict__ xbf,
    const int* __restrict__ rowptr, const int* __restrict__ col,
    float* __restrict__ agg)
{
    int wid = blockIdx.x * 4 + (threadIdx.x >> 6);
    int lane = threadIdx.x & 63;
    int g2 = lane >> 4;        // edge slot 0..3
    int l16 = lane & 15;       // feature quad 0..15
    if (wid >= N_NODES) return;
    int beg = rowptr[wid], end = rowptr[wid + 1];

    float4 acc = make_float4(0.0f, 0.0f, 0.0f, 0.0f);
    for (int e0 = beg; e0 < end; e0 += 16) {
        #pragma unroll
        for (int j = 0; j < 4; ++j) {
            int idx = e0 + j * 4 + g2;
            bool ok = idx < end;
            int c = col[ok ? idx : beg];
            uint2 v = *reinterpret_cast<const uint2*>(&xbf[(size_t)c * F_IN + l16 * 4]);
            if (ok) {
                acc.x += __uint_as_float(v.x << 16);
                acc.y += __uint_as_float(v.x & 0xffff0000u);
                acc.z += __uint_as_float(v.y << 16);
                acc.w += __uint_as_float(v.y & 0xffff0000u);
            }
        }
    }
    acc.x += __shfl_xor(acc.x, 16);
    acc.y += __shfl_xor(acc.y, 16);
    acc.z += __shfl_xor(acc.z, 16);
    acc.w += __shfl_xor(acc.w, 16);
    acc.x += __shfl_xor(acc.x, 32);
    acc.y += __shfl_xor(acc.y, 32);
    acc.z += __shfl_xor(acc.z, 32);
    acc.w += __shfl_xor(acc.w, 32);

    if (g2 == 0) {
        float inv = 1.0f / fmaxf((float)(end - beg), 1.0f);
        float4 o = make_float4(acc.x * inv, acc.y * inv, acc.z * inv, acc.w * inv);
        *reinterpret_cast<float4*>(&agg[(size_t)wid * F_IN + l16 * 4]) = o;
    }
}

// ---------------------------------------------------------------------------
// Weight fragment prep (unchanged).
// ---------------------------------------------------------------------------
__global__ __launch_bounds__(256) void prep_w_kernel(
    const float* __restrict__ W1, const float* __restrict__ W2,
    const float* __restrict__ Win, const float* __restrict__ Wout,
    unsigned short* __restrict__ W1Ahi, unsigned short* __restrict__ W1Alo,
    unsigned short* __restrict__ W2Ahi, unsigned short* __restrict__ W2Alo,
    unsigned short* __restrict__ WinAhi, unsigned short* __restrict__ WinAlo,
    unsigned short* __restrict__ WoutAhi, unsigned short* __restrict__ WoutAlo)
{
    int t = blockIdx.x * 256 + threadIdx.x;
    int lane = t & 63;
    int l15 = lane & 15, g = lane >> 4;
    if (t < 4096) {
        int ht = (t >> 6) & 31, ks = t >> 11;
        int m = ht * 16 + l15;
        int k0 = ks * 32 + g * 8;
        size_t o = ((size_t)(ht * 2 + ks) * 64 + lane) * 8;
        #pragma unroll
        for (int i = 0; i < 8; ++i) {
            float v = W1[(size_t)(k0 + i) * F_HID + m];
            unsigned short hi = f2bf(v);
            W1Ahi[o + i] = hi;
            W1Alo[o + i] = f2bf(v - bf2f(hi));
        }
    } else if (t < 12288) {
        int u = t - 4096;
        int ft = (u >> 6) & 7, ks2 = u >> 9;
        int m = ft * 16 + l15;
        int k0 = ks2 * 32 + g * 8;
        size_t o = ((size_t)(ks2 * 8 + ft) * 64 + lane) * 8;
        #pragma unroll
        for (int i = 0; i < 8; ++i) {
            float v = W2[(size_t)(k0 + i) * F_OUT + m];
            unsigned short hi = f2bf(v);
            W2Ahi[o + i] = hi;
            W2Alo[o + i] = f2bf(v - bf2f(hi));
        }
    } else if (t < 14336) {
        int u = t - 12288;
        const float* W = (u < 1024) ? Win : Wout;
        unsigned short* Ahi = (u < 1024) ? WinAhi : WoutAhi;
        unsigned short* Alo = (u < 1024) ? WinAlo : WoutAlo;
        u &= 1023;
        int ft = (u >> 6) & 7, ks = u >> 9;
        int m = ft * 16 + l15;
        int k0 = ks * 32 + g * 8;
        size_t o = ((size_t)(ks * 8 + ft) * 64 + lane) * 8;
        #pragma unroll
        for (int i = 0; i < 8; ++i) {
            float v = W[(size_t)(k0 + i) * F_OUT + m];
            unsigned short hi = f2bf(v);
            Ahi[o + i] = hi;
            Alo[o + i] = f2bf(v - bf2f(hi));
        }
    }
}

// ---------------------------------------------------------------------------
// SAGE linear via bf16x3 MFMA (unchanged, validated).
// ---------------------------------------------------------------------------
__global__ __launch_bounds__(256) void sage_lin_mfma_kernel(
    const float* __restrict__ agg,
    const unsigned short* __restrict__ WAhi, const unsigned short* __restrict__ WAlo,
    const float* __restrict__ b, float* __restrict__ out)
{
    int tid = threadIdx.x, lane = tid & 63, w = tid >> 6;
    int l15 = lane & 15, g = lane >> 4;
    int n = blockIdx.x * 64 + w * 16 + l15;
    int nc = (n > N_NODES - 1) ? N_NODES - 1 : n;

    short8b bhf[2], blf[2];
    #pragma unroll
    for (int ks = 0; ks < 2; ++ks) {
        const float* pa = &agg[(size_t)nc * F_IN + ks * 32 + g * 8];
        float4 v0 = *reinterpret_cast<const float4*>(pa);
        float4 v1 = *reinterpret_cast<const float4*>(pa + 4);
        float vv[8] = {v0.x, v0.y, v0.z, v0.w, v1.x, v1.y, v1.z, v1.w};
        short8b h8, l8;
        #pragma unroll
        for (int i = 0; i < 8; ++i) {
            short hh, ll;
            split_bf(vv[i], hh, ll);
            h8[i] = hh;
            l8[i] = ll;
        }
        bhf[ks] = h8;
        blf[ks] = l8;
    }

    #pragma unroll
    for (int ft = 0; ft < 8; ++ft) {
        f32x4 acc;
        {
            float4 bv = *reinterpret_cast<const float4*>(&b[ft * 16 + g * 4]);
            acc[0] = bv.x; acc[1] = bv.y; acc[2] = bv.z; acc[3] = bv.w;
        }
        #pragma unroll
        for (int ks = 0; ks < 2; ++ks) {
            size_t o = ((size_t)(ks * 8 + ft) * 64 + lane) * 8;
            short8b ah = *reinterpret_cast<const short8b*>(&WAhi[o]);
            short8b al = *reinterpret_cast<const short8b*>(&WAlo[o]);
            acc = __builtin_amdgcn_mfma_f32_16x16x32_bf16(ah, bhf[ks], acc, 0, 0, 0);
            acc = __builtin_amdgcn_mfma_f32_16x16x32_bf16(ah, blf[ks], acc, 0, 0, 0);
            acc = __builtin_amdgcn_mfma_f32_16x16x32_bf16(al, bhf[ks], acc, 0, 0, 0);
        }
        if (n < N_NODES) {
            float4 o4;
            o4.x = elu_f(acc[0]);
            o4.y = elu_f(acc[1]);
            o4.z = elu_f(acc[2]);
            o4.w = elu_f(acc[3]);
            *reinterpret_cast<float4*>(&out[(size_t)n * F_OUT + ft * 16 + g * 4]) = o4;
        }
    }
}

// Parallel/coalesced sage validate: grid = 4 (one node per block), 128 thr.
// W column loads are coalesced across threads (consecutive f).
__global__ __launch_bounds__(128) void validate_sage_kernel(
    const float* __restrict__ agg,
    const float* __restrict__ W, const float* __restrict__ b,
    const float* __restrict__ outd, int* __restrict__ flag)
{
    __shared__ float sA[F_IN];
    int nn = blockIdx.x;
    int f = threadIdx.x;
    if (f < F_IN) sA[f] = agg[(size_t)nn * F_IN + f];
    __syncthreads();
    float acc = b[f];
    for (int k = 0; k < F_IN; ++k)
        acc = fmaf(sA[k], W[(size_t)k * F_OUT + f], acc);
    float ref = elu_f(acc);
    float got = outd[(size_t)nn * F_OUT + f];
    if (!(fabsf(ref - got) <= 0.01f)) atomicOr(flag, 1);
}

// ---------------------------------------------------------------------------
// Self MLP via bf16x3 MFMA (round-14 validated: LDS-staged W, (256,4)).
// ---------------------------------------------------------------------------
__global__ __launch_bounds__(256, 4) void self_mlp_mfma_kernel(
    const float* __restrict__ x,
    const unsigned short* __restrict__ W1Ahi, const unsigned short* __restrict__ W1Alo,
    const unsigned short* __restrict__ W2Ahi, const unsigned short* __restrict__ W2Alo,
    const float* __restrict__ b1, const float* __restrict__ b2,
    float* __restrict__ out)
{
    __shared__ unsigned short sW1hi[2048], sW1lo[2048];
    __shared__ unsigned short sW2hi[4096], sW2lo[4096];
    __shared__ unsigned short sHhi[4096], sHlo[4096];

    int tid = threadIdx.x, lane = tid & 63, w = tid >> 6;
    int l15 = lane & 15, g = lane >> 4;
    int node0 = blockIdx.x * 128;

    short8b xhi[2][2], xlo[2][2];
    #pragma unroll
    for (int nt = 0; nt < 2; ++nt) {
        int n = node0 + (2 * w + nt) * 16 + l15;
        if (n > N_NODES - 1) n = N_NODES - 1;
        #pragma unroll
        for (int ks = 0; ks < 2; ++ks) {
            const float* px = &x[(size_t)n * F_IN + ks * 32 + g * 8];
            float4 v0 = *reinterpret_cast<const float4*>(px);
            float4 v1 = *reinterpret_cast<const float4*>(px + 4);
            float vv[8] = {v0.x, v0.y, v0.z, v0.w, v1.x, v1.y, v1.z, v1.w};
            short8b h8, l8;
            #pragma unroll
            for (int i = 0; i < 8; ++i) {
                short hh, ll;
                split_bf(vv[i], hh, ll);
                h8[i] = hh;
                l8[i] = ll;
            }
            xhi[nt][ks] = h8;
            xlo[nt][ks] = l8;
        }
    }

    f32x4 acc[8][2];
    #pragma unroll
    for (int ft = 0; ft < 8; ++ft) {
        float4 bv = *reinterpret_cast<const float4*>(&b2[ft * 16 + g * 4]);
        #pragma unroll
        for (int nt = 0; nt < 2; ++nt) {
            acc[ft][nt][0] = bv.x; acc[ft][nt][1] = bv.y;
            acc[ft][nt][2] = bv.z; acc[ft][nt][3] = bv.w;
        }
    }

    for (int c = 0; c < 16; ++c) {
        __syncthreads();
        {
            const float4* s1h = reinterpret_cast<const float4*>(W1Ahi + (size_t)c * 2048);
            const float4* s1l = reinterpret_cast<const float4*>(W1Alo + (size_t)c * 2048);
            reinterpret_cast<float4*>(sW1hi)[tid] = s1h[tid];
            reinterpret_cast<float4*>(sW1lo)[tid] = s1l[tid];
            const float4* s2h = reinterpret_cast<const float4*>(W2Ahi + (size_t)c * 4096);
            const float4* s2l = reinterpret_cast<const float4*>(W2Alo + (size_t)c * 4096);
            reinterpret_cast<float4*>(sW2hi)[tid] = s2h[tid];
            reinterpret_cast<float4*>(sW2hi)[tid + 256] = s2h[tid + 256];
            reinterpret_cast<float4*>(sW2lo)[tid] = s2l[tid];
            reinterpret_cast<float4*>(sW2lo)[tid + 256] = s2l[tid + 256];
        }
        __syncthreads();

        #pragma unroll
        for (int ht = 0; ht < 2; ++ht) {
            #pragma unroll
            for (int nt = 0; nt < 2; ++nt) {
                f32x4 hacc;
                float4 b1v = *reinterpret_cast<const float4*>(&b1[c * 32 + ht * 16 + g * 4]);
                hacc[0] = b1v.x; hacc[1] = b1v.y; hacc[2] = b1v.z; hacc[3] = b1v.w;
                #pragma unroll
                for (int ks = 0; ks < 2; ++ks) {
                    short8b ah = *reinterpret_cast<const short8b*>(&sW1hi[((ht * 2 + ks) * 64 + lane) * 8]);
                    short8b al = *reinterpret_cast<const short8b*>(&sW1lo[((ht * 2 + ks) * 64 + lane) * 8]);
                    hacc = __builtin_amdgcn_mfma_f32_16x16x32_bf16(ah, xhi[nt][ks], hacc, 0, 0, 0);
                    hacc = __builtin_amdgcn_mfma_f32_16x16x32_bf16(ah, xlo[nt][ks], hacc, 0, 0, 0);
                    hacc = __builtin_amdgcn_mfma_f32_16x16x32_bf16(al, xhi[nt][ks], hacc, 0, 0, 0);
                }
                int nodeL = (2 * w + nt) * 16 + l15;
                short4b ph, pl;
                #pragma unroll
                for (int r = 0; r < 4; ++r) {
                    float hv = elu_f(hacc[r]);
                    short hh, ll;
                    split_bf(hv, hh, ll);
                    ph[r] = hh;
                    pl[r] = ll;
                }
                int byte = nodeL * 64 + (ht * 16 + g * 4) * 2;
                byte ^= (nodeL & 7) << 4;
                *reinterpret_cast<short4b*>(reinterpret_cast<char*>(sHhi) + byte) = ph;
                *reinterpret_cast<short4b*>(reinterpret_cast<char*>(sHlo) + byte) = pl;
            }
        }

        short8b bh[2], bl[2];
        #pragma unroll
        for (int nt = 0; nt < 2; ++nt) {
            int nodeL = (2 * w + nt) * 16 + l15;
            int byte = (nodeL * 64 + g * 16) ^ ((nodeL & 7) << 4);
            bh[nt] = *reinterpret_cast<const short8b*>(reinterpret_cast<const char*>(sHhi) + byte);
            bl[nt] = *reinterpret_cast<const short8b*>(reinterpret_cast<const char*>(sHlo) + byte);
        }
        #pragma unroll
        for (int ft = 0; ft < 8; ++ft) {
            short8b ah = *reinterpret_cast<const short8b*>(&sW2hi[(ft * 64 + lane) * 8]);
            short8b al = *reinterpret_cast<const short8b*>(&sW2lo[(ft * 64 + lane) * 8]);
            #pragma unroll
            for (int nt = 0; nt < 2; ++nt) {
                acc[ft][nt] = __builtin_amdgcn_mfma_f32_16x16x32_bf16(ah, bh[nt], acc[ft][nt], 0, 0, 0);
                acc[ft][nt] = __builtin_amdgcn_mfma_f32_16x16x32_bf16(ah, bl[nt], acc[ft][nt], 0, 0, 0);
                acc[ft][nt] = __builtin_amdgcn_mfma_f32_16x16x32_bf16(al, bh[nt], acc[ft][nt], 0, 0, 0);
            }
        }
    }

    #pragma unroll
    for (int ft = 0; ft < 8; ++ft) {
        #pragma unroll
        for (int nt = 0; nt < 2; ++nt) {
            int n = node0 + (2 * w + nt) * 16 + l15;
            if (n < N_NODES) {
                float4 o;
                o.x = elu_f(acc[ft][nt][0]);
                o.y = elu_f(acc[ft][nt][1]);
                o.z = elu_f(acc[ft][nt][2]);
                o.w = elu_f(acc[ft][nt][3]);
                *reinterpret_cast<float4*>(&out[(size_t)n * F_OUT + ft * 16 + g * 4]) = o;
            }
        }
    }
}

// Parallel/coalesced self validate: grid = 4 (one node per block), 256 thr.
__global__ __launch_bounds__(256) void validate_kernel(
    const float* __restrict__ x,
    const float* __restrict__ W1, const float* __restrict__ b1,
    const float* __restrict__ W2, const float* __restrict__ b2,
    const float* __restrict__ out_self, int* __restrict__ flag)
{
    __shared__ float h[F_HID];
    __shared__ float sX[F_IN];
    int nn = blockIdx.x;
    int tid = threadIdx.x;
    if (tid < F_IN) sX[tid] = x[(size_t)nn * F_IN + tid];
    __syncthreads();
    #pragma unroll
    for (int jj = 0; jj < 2; ++jj) {
        int j = tid * 2 + jj;
        float acc = b1[j];
        for (int k = 0; k < F_IN; ++k)
            acc = fmaf(sX[k], W1[(size_t)k * F_HID + j], acc);
        h[j] = elu_f(acc);
    }
    __syncthreads();
    if (tid < F_OUT) {
        int f = tid;
        float acc = b2[f];
        for (int j = 0; j < F_HID; ++j)
            acc = fmaf(h[j], W2[(size_t)j * F_OUT + f], acc);
        float ref = elu_f(acc);
        float got = out_self[(size_t)nn * F_OUT + f];
        if (!(fabsf(ref - got) <= 0.01f)) atomicOr(flag, 1);
    }
}

// ---------------------------------------------------------------------------
// Flag-gated repairs.
// ---------------------------------------------------------------------------
__global__ __launch_bounds__(256) void gather_repair_kernel(
    const int* __restrict__ flag,
    const float* __restrict__ x,
    const int* __restrict__ rowptr, const int* __restrict__ col,
    float* __restrict__ agg)
{
    if (flag[0] == 0) return;
    int f = threadIdx.x & 63;
    for (int bb = blockIdx.x; bb < 25000; bb += gridDim.x) {
        int wid = bb * 4 + (threadIdx.x >> 6);
        if (wid >= N_NODES) continue;
        int beg = rowptr[wid];
        int end = rowptr[wid + 1];
        float acc = 0.0f;
        for (int e = beg; e < end; ++e)
            acc += x[(size_t)col[e] * F_IN + f];
        agg[(size_t)wid * F_IN + f] = acc / fmaxf((float)(end - beg), 1.0f);
    }
}

__global__ __launch_bounds__(256) void sage_lin_repair_kernel(
    const int* __restrict__ flag,
    const float* __restrict__ agg,
    const float* __restrict__ W, const float* __restrict__ b,
    float* __restrict__ out)
{
    if (flag[0] == 0) return;

    __shared__ float sW[F_IN][F_OUT];
    __shared__ float sA[16][68];

    int tid = threadIdx.x;
    int og = tid & 15;
    int nl = tid >> 4;

    for (int bb = blockIdx.x; bb < 6250; bb += gridDim.x) {
        int node0 = bb * 16;
        __syncthreads();
        #pragma unroll
        for (int it = 0; it < 8; ++it) {
            int i = tid + it * 256;
            int k = (i * 4) >> 7, ff = (i * 4) & 127;
            *reinterpret_cast<float4*>(&sW[k][ff]) =
                *reinterpret_cast<const float4*>(&W[(size_t)i * 4]);
        }
        {
            int nn = node0 + (tid >> 4), c4 = tid & 15;
            *reinterpret_cast<float4*>(&sA[tid >> 4][c4 * 4]) =
                *reinterpret_cast<const float4*>(&agg[(size_t)nn * F_IN + c4 * 4]);
        }
        __syncthreads();

        int n = node0 + nl;
        float acc[8];
        {
            float4 bl = *reinterpret_cast<const float4*>(&b[og * 4]);
            float4 bh = *reinterpret_cast<const float4*>(&b[64 + og * 4]);
            acc[0] = bl.x; acc[1] = bl.y; acc[2] = bl.z; acc[3] = bl.w;
            acc[4] = bh.x; acc[5] = bh.y; acc[6] = bh.z; acc[7] = bh.w;
        }
        for (int k = 0; k < F_IN; ++k) {
            float a = sA[nl][k];
            float4 w0 = *reinterpret_cast<const float4*>(&sW[k][og * 4]);
            float4 w1 = *reinterpret_cast<const float4*>(&sW[k][64 + og * 4]);
            acc[0] = fmaf(a, w0.x, acc[0]);
            acc[1] = fmaf(a, w0.y, acc[1]);
            acc[2] = fmaf(a, w0.z, acc[2]);
            acc[3] = fmaf(a, w0.w, acc[3]);
            acc[4] = fmaf(a, w1.x, acc[4]);
            acc[5] = fmaf(a, w1.y, acc[5]);
            acc[6] = fmaf(a, w1.z, acc[6]);
            acc[7] = fmaf(a, w1.w, acc[7]);
        }
        float4 o0 = make_float4(elu_f(acc[0]), elu_f(acc[1]), elu_f(acc[2]), elu_f(acc[3]));
        float4 o1 = make_float4(elu_f(acc[4]), elu_f(acc[5]), elu_f(acc[6]), elu_f(acc[7]));
        *reinterpret_cast<float4*>(&out[(size_t)n * F_OUT + og * 4]) = o0;
        *reinterpret_cast<float4*>(&out[(size_t)n * F_OUT + 64 + og * 4]) = o1;
    }
}

__global__ __launch_bounds__(256, 3) void self_mlp_repair_kernel(
    const int* __restrict__ flag,
    const float* __restrict__ x,
    const float* __restrict__ W1, const float* __restrict__ b1,
    const float* __restrict__ W2, const float* __restrict__ b2,
    float* __restrict__ out)
{
    if (flag[0] == 0) return;

    __shared__ float sXT[F_IN][128];
    __shared__ float sW1[F_IN][16];
    __shared__ float sHT[16][128];
    __shared__ float sW2[16][128];
    __shared__ float sb1[16];

    int tid = threadIdx.x;
    int node0 = blockIdx.x * 128;

    #pragma unroll
    for (int it = 0; it < 8; ++it) {
        int fid = tid + it * 256;
        int node = fid & 127, k4 = fid >> 7;
        int n = node0 + node;
        if (n > N_NODES - 1) n = N_NODES - 1;
        float4 v = *reinterpret_cast<const float4*>(&x[(size_t)n * F_IN + k4 * 4]);
        sXT[k4 * 4 + 0][node] = v.x;
        sXT[k4 * 4 + 1][node] = v.y;
        sXT[k4 * 4 + 2][node] = v.z;
        sXT[k4 * 4 + 3][node] = v.w;
    }

    int og = tid & 15;
    int ng = tid >> 4;
    int ng1 = tid & 31;
    int hg = tid >> 5;

    float acc[8][8];
    {
        float4 bl = *reinterpret_cast<const float4*>(&b2[og * 4]);
        float4 bh = *reinterpret_cast<const float4*>(&b2[64 + og * 4]);
        #pragma unroll
        for (int i = 0; i < 8; ++i) {
            acc[i][0] = bl.x; acc[i][1] = bl.y; acc[i][2] = bl.z; acc[i][3] = bl.w;
            acc[i][4] = bh.x; acc[i][5] = bh.y; acc[i][6] = bh.z; acc[i][7] = bh.w;
        }
    }

    for (int c = 0; c < 32; ++c) {
        int hid0 = c * 16;
        __syncthreads();

        {
            int k = tid >> 2, h4 = tid & 3;
            float4 v = *reinterpret_cast<const float4*>(&W1[(size_t)k * F_HID + hid0 + h4 * 4]);
            *reinterpret_cast<float4*>(&sW1[k][h4 * 4]) = v;
        }
        #pragma unroll
        for (int it = 0; it < 2; ++it) {
            int fid = tid + it * 256;
            int j = fid >> 5, f4 = fid & 31;
            float4 v = *reinterpret_cast<const float4*>(&W2[(size_t)(hid0 + j) * F_OUT + f4 * 4]);
            *reinterpret_cast<float4*>(&sW2[j][f4 * 4]) = v;
        }
        if (tid < 16) sb1[tid] = b1[hid0 + tid];
        __syncthreads();

        {
            float h0[4], h1[4];
            float bb0 = sb1[hg * 2], bb1 = sb1[hg * 2 + 1];
            #pragma unroll
            for (int i = 0; i < 4; ++i) { h0[i] = bb0; h1[i] = bb1; }
            #pragma unroll 8
            for (int k = 0; k < F_IN; ++k) {
                float4 a = *reinterpret_cast<const float4*>(&sXT[k][ng1 * 4]);
                float w0 = sW1[k][hg * 2];
                float w1 = sW1[k][hg * 2 + 1];
                h0[0] = fmaf(w0, a.x, h0[0]);
                h0[1] = fmaf(w0, a.y, h0[1]);
                h0[2] = fmaf(w0, a.z, h0[2]);
                h0[3] = fmaf(w0, a.w, h0[3]);
                h1[0] = fmaf(w1, a.x, h1[0]);
                h1[1] = fmaf(w1, a.y, h1[1]);
                h1[2] = fmaf(w1, a.z, h1[2]);
                h1[3] = fmaf(w1, a.w, h1[3]);
            }
            float4 o0 = make_float4(elu_f(h0[0]), elu_f(h0[1]), elu_f(h0[2]), elu_f(h0[3]));
            float4 o1 = make_float4(elu_f(h1[0]), elu_f(h1[1]), elu_f(h1[2]), elu_f(h1[3]));
            *reinterpret_cast<float4*>(&sHT[hg * 2][ng1 * 4]) = o0;
            *reinterpret_cast<float4*>(&sHT[hg * 2 + 1][ng1 * 4]) = o1;
        }
        __syncthreads();

        #pragma unroll 2
        for (int k = 0; k < 16; ++k) {
            float4 ha = *reinterpret_cast<const float4*>(&sHT[k][ng * 4]);
            float4 hb = *reinterpret_cast<const float4*>(&sHT[k][64 + ng * 4]);
            float4 wa = *reinterpret_cast<const float4*>(&sW2[k][og * 4]);
            float4 wb = *reinterpret_cast<const float4*>(&sW2[k][64 + og * 4]);
            float hv[8] = {ha.x, ha.y, ha.z, ha.w, hb.x, hb.y, hb.z, hb.w};
            float wv[8] = {wa.x, wa.y, wa.z, wa.w, wb.x, wb.y, wb.z, wb.w};
            #pragma unroll
            for (int i = 0; i < 8; ++i) {
                #pragma unroll
                for (int j = 0; j < 8; ++j) {
                    acc[i][j] = fmaf(hv[i], wv[j], acc[i][j]);
                }
            }
        }
    }

    #pragma unroll
    for (int i = 0; i < 8; ++i) {
        int n = node0 + (i < 4 ? ng * 4 + i : 64 + ng * 4 + (i - 4));
        if (n < N_NODES) {
            float4 o0 = make_float4(elu_f(acc[i][0]), elu_f(acc[i][1]),
                                    elu_f(acc[i][2]), elu_f(acc[i][3]));
            float4 o1 = make_float4(elu_f(acc[i][4]), elu_f(acc[i][5]),
                                    elu_f(acc[i][6]), elu_f(acc[i][7]));
            *reinterpret_cast<float4*>(&out[(size_t)n * F_OUT + og * 4]) = o0;
            *reinterpret_cast<float4*>(&out[(size_t)n * F_OUT + 64 + og * 4]) = o1;
        }
    }
}

// ---------------------------------------------------------------------------

extern "C" void kernel_launch(void* const* d_in, const int* in_sizes, int n_in,
                              void* d_out, int out_size, void* d_ws, size_t ws_size,
                              hipStream_t stream) {
    const float* x     = (const float*)d_in[0];
    const int*   ei    = (const int*)d_in[1];
    const float* W_in  = (const float*)d_in[2];
    const float* b_in  = (const float*)d_in[3];
    const float* W_out = (const float*)d_in[4];
    const float* b_out = (const float*)d_in[5];
    const float* W1    = (const float*)d_in[6];
    const float* b1    = (const float*)d_in[7];
    const float* W2    = (const float*)d_in[8];
    const float* b2    = (const float*)d_in[9];
    float* out = (float*)d_out;

    const int* src = ei;
    const int* dst = ei + N_EDGES;

    int* I = (int*)d_ws;
    int* rowptr_in  = I;                       // 100001
    int* rowptr_out = I + 100001;              // 100001
    int* col_in     = I + 200002;              // 1,000,000
    int* col_out    = I + 1200002;             // 1,000,000
    int* deg_in     = I + 2200002;             // 100,000  <- zeroed start
    int* deg_out    = I + 2300002;             // 100,000
    int* cur_in     = I + 2400002;             // 100,000  (repair scratch)
    int* cur_out    = I + 2500002;             // 100,000  <- zeroed end
    int* bsum_in    = I + 2600002;             // 128
    int* bsum_out   = I + 2600130;             // 128
    int* flagM      = I + 2600260;             // self MFMA
    int* flagS      = I + 2600261;             // sage MFMA
    int* flagC      = I + 2600262;             // CSR multisplit
    float* agg      = (float*)(I + 2600512);   // 100000*64 floats (25.6 MB)
    unsigned short* WF = (unsigned short*)(I + 9000512);
    unsigned short* W1Ahi  = WF;
    unsigned short* W1Alo  = WF + 32768;
    unsigned short* W2Ahi  = WF + 65536;
    unsigned short* W2Alo  = WF + 131072;
    unsigned short* WinAhi = WF + 196608;
    unsigned short* WinAlo = WF + 204800;
    unsigned short* WoutAhi= WF + 212992;
    unsigned short* WoutAlo= WF + 221184;      // ends at 229376 halfs
    unsigned short* xbf    = (unsigned short*)(I + 9120512);  // 6.4M halfs (12.8 MB)

    unsigned int* tmp_in  = (unsigned int*)agg;            // alias agg (dead until gather)
    unsigned int* tmp_out = (unsigned int*)agg + 1000000;
    int* bcur_in  = deg_in;                                // alias deg (dead after scans)
    int* bcur_out = deg_out;

    hipMemsetAsync(deg_in, 0, 400000 * sizeof(int), stream);
    hipMemsetAsync(flagM, 0, 3 * sizeof(int), stream);

    prep_w_kernel<<<56, 256, 0, stream>>>(W1, W2, W_in, W_out,
                                          W1Ahi, W1Alo, W2Ahi, W2Alo,
                                          WinAhi, WinAlo, WoutAhi, WoutAlo);
    prep_x_kernel<<<6250, 256, 0, stream>>>(x, xbf);

    const int eb = (N_EDGES + 255) / 256;      // 3907
    hist_kernel<<<eb, 256, 0, stream>>>(src, dst, deg_in, deg_out);

    // Fused dual-direction scans.
    scan_block_kernel<<<2 * SB, 256, 0, stream>>>(deg_in, deg_out,
                                                  rowptr_in, rowptr_out,
                                                  bsum_in, bsum_out, N_NODES);
    scan_top_kernel<<<2, 128, 0, stream>>>(bsum_in, bsum_out, SB);
    scan_add_kernel<<<2 * AB, 256, 0, stream>>>(rowptr_in, rowptr_out,
                                                bsum_in, bsum_out,
                                                bcur_in, bcur_out,
                                                N_NODES, N_EDGES);

    // Fused dual-direction multisplit pass 1, then pass 2.
    msplit_scatter_kernel<<<2 * P1B, 512, 0, stream>>>(src, dst,
                                                       bcur_in, bcur_out,
                                                       tmp_in, tmp_out);
    msplit_place_kernel<<<2 * NB, 256, 0, stream>>>(tmp_in, tmp_out,
                                                    rowptr_in, rowptr_out,
                                                    col_in, col_out, flagC);
    place_repair_kernel<<<eb, 256, 0, stream>>>(flagC, src, dst,
                                                rowptr_in, rowptr_out,
                                                cur_in, cur_out, col_in, col_out);

    const int gb = (N_NODES + 3) / 4;          // 25000
    const int mb = (N_NODES + 63) / 64;        // 1563
    float* out_in   = out;
    float* out_out  = out + (size_t)N_NODES * F_OUT;
    float* out_self = out + 2 * (size_t)N_NODES * F_OUT;

    gather_mean_kernel<<<gb, 256, 0, stream>>>(xbf, rowptr_in, col_in, agg);
    sage_lin_mfma_kernel<<<mb, 256, 0, stream>>>(agg, WinAhi, WinAlo, b_in, out_in);
    validate_sage_kernel<<<4, 128, 0, stream>>>(agg, W_in, b_in, out_in, flagS);

    gather_mean_kernel<<<gb, 256, 0, stream>>>(xbf, rowptr_out, col_out, agg);
    sage_lin_mfma_kernel<<<mb, 256, 0, stream>>>(agg, WoutAhi, WoutAlo, b_out, out_out);
    validate_sage_kernel<<<4, 128, 0, stream>>>(agg, W_out, b_out, out_out, flagS);

    self_mlp_mfma_kernel<<<782, 256, 0, stream>>>(x, W1Ahi, W1Alo, W2Ahi, W2Alo,
                                                  b1, b2, out_self);
    validate_kernel<<<4, 256, 0, stream>>>(x, W1, b1, W2, b2, out_self, flagM);

    self_mlp_repair_kernel<<<782, 256, 0, stream>>>(flagM, x, W1, b1, W2, b2, out_self);
    gather_repair_kernel<<<2048, 256, 0, stream>>>(flagS, x, rowptr_in, col_in, agg);
    sage_lin_repair_kernel<<<2048, 256, 0, stream>>>(flagS, agg, W_in, b_in, out_in);
    gather_repair_kernel<<<2048, 256, 0, stream>>>(flagS, x, rowptr_out, col_out, agg);
    sage_lin_repair_kernel<<<2048, 256, 0, stream>>>(flagS, agg, W_out, b_out, out_out);
}